// Round 6
// baseline (662.840 us; speedup 1.0000x reference)
//
#include <hip/hip_runtime.h>
#include <math.h>

#define N_E 2048
#define N_U 4096
#define N_SVC 1024
#define KT 16
#define STRX (KT*N_E*32)   // per-stream x buffer stride (floats)
#define YSTR (KT*N_E*32)   // per-stream y buffer stride (shorts)
#define TSTR (KT*8*N_E)    // per-stream T^T stride (floats)

typedef __attribute__((ext_vector_type(8))) short short8;   // 8 bf16 (4 VGPRs)
typedef __attribute__((ext_vector_type(4))) float f32x4;

__device__ __forceinline__ float sigf(float x){ return 1.0f/(1.0f+__expf(-x)); }
__device__ __forceinline__ float tanhfast(float x){ return 1.0f - 2.0f/(__expf(2.0f*x)+1.0f); }
__device__ __forceinline__ short f2bf(float f){
  union { float f; unsigned u; } x; x.f = f;
  unsigned r = x.u + 0x7FFFu + ((x.u >> 16) & 1u);
  return (short)(r >> 16);
}
__device__ __forceinline__ float bf2f(unsigned short u){
  union { unsigned u; float f; } x; x.u = ((unsigned)u) << 16; return x.f;
}
// expm1 via 4-term Taylor: rel err <1e-5 for d in [0, 0.5]; d here is ~<0.05
__device__ __forceinline__ float expm1t(float d){
  float t = fmaf(d, 1.f/24.f, 1.f/6.f);
  t = fmaf(d, t, 0.5f);
  t = fmaf(d, t, 1.f);
  return d*t;
}

// ---------------- embeddings: srv_emb (2048x32), svc_emb (1024x32) ----------------
__global__ void k_embed(const int* __restrict__ srv_attr, const int* __restrict__ svc_attr,
                        const float* __restrict__ srv_tab0, const float* __restrict__ srv_lvl,
                        const float* __restrict__ svc_tab0, const float* __restrict__ svc_lvl,
                        float* __restrict__ srv_emb, float* __restrict__ svc_emb) {
  int idx = blockIdx.x*256 + threadIdx.x;       // (2048+1024) rows * 32 cols
  int r = idx >> 5, c = idx & 31;
  int seg = c >> 3, cc = c & 7;
  if (r < N_E) {
    int a = srv_attr[r*4 + seg];
    srv_emb[r*32 + c] = (seg==0) ? srv_tab0[a*8+cc] : srv_lvl[((seg-1)*10 + a)*8 + cc];
  } else {
    int r2 = r - N_E;
    if (r2 < N_SVC) {
      int a = svc_attr[r2*4 + seg];
      svc_emb[r2*32 + c] = (seg==0) ? svc_tab0[a*8+cc] : svc_lvl[((seg-1)*10 + a)*8 + cc];
    }
  }
}

// ---------------- LSTM: 16 lanes per user, lane j owns hidden unit j ----------------
__global__ __launch_bounds__(256) void k_lstm(const float* __restrict__ usr_tab, const float* __restrict__ tra,
                       const float* __restrict__ Wih, const float* __restrict__ Whh,
                       const float* __restrict__ bih, const float* __restrict__ bhh,
                       float* __restrict__ tra_feat) {
  __shared__ float sWih[64*12];
  __shared__ float sWhh[64*16];
  __shared__ float sB[64];
  int tid = threadIdx.x;
  for (int i = tid; i < 64*12; i += 256) sWih[i] = Wih[i];
  for (int i = tid; i < 64*16; i += 256) sWhh[i] = Whh[i];
  if (tid < 64) sB[tid] = bih[tid] + bhh[tid];
  __syncthreads();
  int j  = tid & 15;
  int u  = blockIdx.x*16 + (tid >> 4);
  float xe[8];
  #pragma unroll
  for (int k=0;k<8;k++) xe[k] = usr_tab[u*8+k];
  float h = 0.f, c = 0.f;
  for (int t=0;t<KT;t++) {
    float gi = sB[j], gf = sB[16+j], gg = sB[32+j], go = sB[48+j];
    #pragma unroll
    for (int k=0;k<8;k++) {
      float v = xe[k];
      gi += sWih[j*12+k]*v;      gf += sWih[(16+j)*12+k]*v;
      gg += sWih[(32+j)*12+k]*v; go += sWih[(48+j)*12+k]*v;
    }
    #pragma unroll
    for (int k=0;k<4;k++) {
      float v = tra[((size_t)t*N_U + u)*4 + k];
      gi += sWih[j*12+8+k]*v;      gf += sWih[(16+j)*12+8+k]*v;
      gg += sWih[(32+j)*12+8+k]*v; go += sWih[(48+j)*12+8+k]*v;
    }
    #pragma unroll
    for (int jj=0;jj<16;jj++) {
      float hv = __shfl(h, jj, 16);
      gi += sWhh[j*16+jj]*hv;      gf += sWhh[(16+j)*16+jj]*hv;
      gg += sWhh[(32+j)*16+jj]*hv; go += sWhh[(48+j)*16+jj]*hv;
    }
    c = sigf(gf)*c + sigf(gi)*tanhfast(gg);
    h = sigf(go)*tanhfast(c);
  }
  tra_feat[u*16 + j] = h;
}

// ---------------- ep/ea = edge @ peW^T + b : only t in [5,15] ----------------
__global__ void k_pe(const float* __restrict__ edge,
                     const float* __restrict__ Wp, const float* __restrict__ bp,
                     const float* __restrict__ Wa, const float* __restrict__ ba,
                     float* __restrict__ ep, float* __restrict__ ea) {
  int idx = blockIdx.x*256 + threadIdx.x;        // s(2)*t(11)*n(2048)*c(8) = 360448
  int c = idx & 7; int rest = idx >> 3;
  int n = rest & 2047; rest >>= 11;              // rest in [0, 22)
  int t = 5 + (rest % 11); int s = rest / 11;
  const float* W = s ? Wa : Wp; const float* b = s ? ba : bp;
  const float* e = edge + ((size_t)t*N_E + n)*11;
  float acc = b[c];
  #pragma unroll
  for (int k=0;k<11;k++) acc += e[k]*W[c*11+k];
  (s ? ea : ep)[((size_t)t*N_E + n)*8 + c] = acc;
}

// ---------------- Tt[t][v][n] = (ep[t] @ (E2[t].E1))^T : only t in [5,15] ----------------
__global__ void k_T(const float* __restrict__ epp, const float* __restrict__ epa,
                    const float* __restrict__ E1p, const float* __restrict__ E2p,
                    const float* __restrict__ E1a, const float* __restrict__ E2a,
                    float* __restrict__ Ttp, float* __restrict__ Tta) {
  __shared__ float sM[64];
  int s = blockIdx.x / 11, t = 5 + blockIdx.x % 11;
  const float* E1 = s ? E1a : E1p;
  const float* E2 = s ? E2a : E2p;
  const float* ep = (s ? epa : epp) + (size_t)t*N_E*8;
  float* Tt = (s ? Tta : Ttp) + (size_t)t*8*N_E;
  int tid = threadIdx.x;
  if (tid < 64) {
    int u = tid >> 3, v = tid & 7;
    float m = 0.f;
    #pragma unroll
    for (int o=0;o<8;o++) m += E2[t*8+o]*E1[(o*8+u)*8+v];
    sM[u*8+v] = m;
  }
  __syncthreads();
  for (int i = tid; i < N_E; i += 256) {
    float e[8];
    const float4* g4 = (const float4*)(ep + (size_t)i*8);
    float4 a = g4[0], b = g4[1];
    e[0]=a.x; e[1]=a.y; e[2]=a.z; e[3]=a.w; e[4]=b.x; e[5]=b.y; e[6]=b.z; e[7]=b.w;
    #pragma unroll
    for (int v=0;v<8;v++) {
      float acc = 0.f;
      #pragma unroll
      for (int u=0;u<8;u++) acc += e[u]*sM[u*8+v];
      Tt[(size_t)v*N_E + i] = acc;   // coalesced across lanes
    }
  }
}

// --------- softmax row partials: partC[s,t,sp,n] = sum_{m in split sp} exp(relu(T[n].ep[m])) ---------
__global__ __launch_bounds__(256) void k_stats(const float* __restrict__ Ttp, const float* __restrict__ Tta,
                        const float* __restrict__ epp, const float* __restrict__ epa,
                        float* __restrict__ partC) {
  __shared__ float sE[256*8];   // 8 KiB
  int s = blockIdx.z, t = 5 + blockIdx.y;
  int ntile = blockIdx.x & 7, sp = blockIdx.x >> 3;
  int n = ntile*256 + threadIdx.x;
  const float* Tt = (s ? Tta : Ttp) + (size_t)t*8*N_E;
  const float* E = (s ? epa : epp) + (size_t)t*N_E*8;
  int tid = threadIdx.x;
  float tr[8];
  #pragma unroll
  for (int v=0;v<8;v++) tr[v] = Tt[(size_t)v*N_E + n];   // coalesced
  int m0 = sp*256;
  {
    const float4* ge = (const float4*)(E + (size_t)m0*8);
    float4* se = (float4*)sE;
    for (int i = tid; i < 512; i += 256) se[i] = ge[i];
  }
  __syncthreads();
  float psum = 0.f;
  #pragma unroll 4
  for (int m = 0; m < 256; m++) {
    float d = 0.f;
    #pragma unroll
    for (int v=0;v<8;v++) d = fmaf(sE[m*8+v], tr[v], d);
    psum += __expf(fmaxf(d, 0.f));
  }
  partC[(((size_t)s*KT + t)*8 + sp)*N_E + n] = psum;
}

// ---------------- Zinv = 1 / (sum of 8 partials), t in [5,15] ----------------
__global__ void k_zinv(const float* __restrict__ partC, float* __restrict__ Z) {
  int i = blockIdx.x*256 + threadIdx.x;   // 2*11*2048 = 45056
  int n = i & 2047; int stp = i >> 11;    // [0,22)
  int s = stp / 11, t = 5 + stp % 11;
  float a = 0.f;
  #pragma unroll
  for (int sp=0;sp<8;sp++) a += partC[(((size_t)s*KT + t)*8 + sp)*N_E + n];
  Z[((size_t)s*KT + t)*N_E + n] = 1.0f/a;
}

// ---------------- x0 = proj(load / svc_tot) : (16,2048,32) x2 ----------------
__global__ void k_proj(const float* __restrict__ loadx, const float* __restrict__ svcx,
                       const float* __restrict__ Wp, const float* __restrict__ bp,
                       const float* __restrict__ Wa, const float* __restrict__ ba,
                       float* __restrict__ x0p, float* __restrict__ x0a) {
  int idx = blockIdx.x*256 + threadIdx.x;        // s t n g : 21 bits
  int g = idx & 31; int rest = idx >> 5;
  int n = rest & 2047; rest >>= 11; int t = rest & 15; int s = rest >> 4;
  const float* in = (s ? svcx : loadx) + ((size_t)t*N_E + n)*3;
  const float* W = s ? Wa : Wp; const float* b = s ? ba : bp;
  float acc = b[g];
  #pragma unroll
  for (int c=0;c<3;c++) acc += in[c]*W[g*3+c];
  (s ? x0a : x0p)[((size_t)t*N_E + n)*32 + g] = acc;
}

// ------- dilated causal conv (kernel 3) + ReLU, scaled by Zinv[n], output bf16 -------
__global__ __launch_bounds__(256) void k_conv(const float* __restrict__ xp, const float* __restrict__ xa,
                       const float* __restrict__ Wtp, const float* __restrict__ Wta,
                       const float* __restrict__ btp, const float* __restrict__ bta,
                       const float* __restrict__ Zg,
                       unsigned short* __restrict__ yp, unsigned short* __restrict__ ya,
                       int layer, int dd, int tbase, int tstep) {
  __shared__ float sW[3*32*32];
  __shared__ float sX[8][3][32];
  int s = blockIdx.z;
  int t = tbase + blockIdx.y*tstep;
  const float* x  = s ? xa : xp;
  const float* Wt = (s ? Wta : Wtp) + (size_t)layer*3*32*32;
  const float* bt = (s ? bta : btp) + layer*32;
  unsigned short* y = s ? ya : yp;
  int tid = threadIdx.x;
  for (int i = tid; i < 3*32*32; i += 256) sW[i] = Wt[i];
  int n0 = blockIdx.x*8;
  for (int i = tid; i < 768; i += 256) {
    int f = i & 31; int nn = (i>>5)&7; int j = i >> 8;
    int tt = t - (2-j)*dd;
    sX[nn][j][f] = (tt >= 0) ? x[((size_t)tt*N_E + n0+nn)*32 + f] : 0.f;
  }
  __syncthreads();
  int g = tid & 31, nn = tid >> 5;
  float acc = bt[g];
  #pragma unroll
  for (int j=0;j<3;j++)
    #pragma unroll
    for (int f=0;f<32;f++) acc += sX[nn][j][f]*sW[(j*32+f)*32+g];
  float zi = Zg[((size_t)s*KT + t)*N_E + n0+nn];
  y[((size_t)t*N_E + n0+nn)*32 + g] = (unsigned short)f2bf(fmaxf(acc, 0.f)*zi);
}

// ---------------- ysum[s,ty,f] = sum_n y'[n,f] (f32 colsum of bf16 y') ----------------
__global__ __launch_bounds__(256) void k_ysum(const unsigned short* __restrict__ yp,
                       const unsigned short* __restrict__ ya,
                       float* __restrict__ ysumb, int tbase, int tstep, int nt) {
  __shared__ float red[256];
  int ty = blockIdx.x, s = blockIdx.y;
  int t = tbase + ty*tstep;
  const unsigned short* y = (s ? ya : yp) + (size_t)t*N_E*32;
  int tid = threadIdx.x;
  int f = tid & 31, sl = tid >> 5;
  float a = 0.f;
  for (int nn = sl*256; nn < sl*256 + 256; nn++) a += bf2f(y[(size_t)nn*32 + f]);
  red[tid] = a;
  __syncthreads();
  if (tid < 32) {
    float acc = 0.f;
    #pragma unroll
    for (int k=0;k<8;k++) acc += red[tid + 32*k];
    ysumb[((size_t)s*nt + ty)*32 + tid] = acc;
  }
}

// --------- MFMA mixing: part[m,f] = sum_n q[n,m] * y'[n,f],  q = expm1(relu(T[n].ep[m])) ---------
// T^T and bf16 Y precomputed globally; per-chunk reg-staged pipeline (issue next chunk's
// 3 float4 loads before computing current -> HBM latency hidden under compute).
__global__ __launch_bounds__(256) void k_mixm(const float* __restrict__ Ttp, const float* __restrict__ Tta,
                      const float* __restrict__ epp, const float* __restrict__ epa,
                      const unsigned short* __restrict__ ybp, const unsigned short* __restrict__ yba,
                      float* __restrict__ part,
                      int tbase, int tstep, int nt, int nsplit) {
  __shared__ float sTt[8*132];             // 4.1 KiB, T^T chunk, pad 132
  __shared__ unsigned short sYb[128*34];   // 8.5 KiB, bf16 y chunk, pad 34
  int s = blockIdx.z, ty = blockIdx.y;
  int t = tbase + ty*tstep;
  int mtile = blockIdx.x & 31, split = blockIdx.x >> 5;
  int tid = threadIdx.x;
  int w = tid >> 6, lane = tid & 63;
  int g = lane >> 4, fc = lane & 15;
  int m0 = mtile*64 + w*16;
  const float* Tt = (s ? Tta : Ttp) + (size_t)t*8*N_E;
  const float* ep = (s ? epa : epp) + (size_t)t*N_E*8;
  const unsigned short* yb = (s ? yba : ybp) + (size_t)t*N_E*32;
  float er[8];
  {
    const float4* gep = (const float4*)(ep + (size_t)(m0 + fc)*8);
    float4 a = gep[0], b = gep[1];
    er[0]=a.x; er[1]=a.y; er[2]=a.z; er[3]=a.w;
    er[4]=b.x; er[5]=b.y; er[6]=b.z; er[7]=b.w;
  }
  f32x4 acc0 = {0.f,0.f,0.f,0.f}, acc1 = {0.f,0.f,0.f,0.f};
  int n0 = split*(N_E/nsplit), n1 = n0 + (N_E/nsplit);   // multiples of 128
  int tv = tid >> 5, tc = tid & 31;       // T-stage coords: row v, col-quad
  float4 tReg, yR0, yR1;
  {
    tReg = *(const float4*)(Tt + (size_t)tv*N_E + n0 + tc*4);
    const float4* gy = (const float4*)(yb + (size_t)n0*32);
    yR0 = gy[tid]; yR1 = gy[tid + 256];
  }
  for (int c0 = n0; c0 < n1; c0 += 128) {
    __syncthreads();
    // write staged regs to LDS
    *(float4*)&sTt[tv*132 + tc*4] = tReg;
    {
      union { float4 f; unsigned u[4]; } cv;
      cv.f = yR0;
      unsigned* d0 = (unsigned*)&sYb[(tid>>2)*34 + (tid&3)*8];
      d0[0]=cv.u[0]; d0[1]=cv.u[1]; d0[2]=cv.u[2]; d0[3]=cv.u[3];
      cv.f = yR1;
      unsigned* d1 = (unsigned*)&sYb[(64 + (tid>>2))*34 + (tid&3)*8];
      d1[0]=cv.u[0]; d1[1]=cv.u[1]; d1[2]=cv.u[2]; d1[3]=cv.u[3];
    }
    __syncthreads();
    if (c0 + 128 < n1) {   // issue next chunk's loads; latency hides under compute below
      tReg = *(const float4*)(Tt + (size_t)tv*N_E + (c0+128) + tc*4);
      const float4* gy = (const float4*)(yb + (size_t)(c0+128)*32);
      yR0 = gy[tid]; yR1 = gy[tid + 256];
    }
    #pragma unroll
    for (int sub = 0; sub < 4; sub++) {
      int rbase = sub*32 + g*8;
      f32x4 dA = {0.f,0.f,0.f,0.f}, dB = {0.f,0.f,0.f,0.f};
      #pragma unroll
      for (int v=0; v<8; v++) {
        const f32x4* tvp = (const f32x4*)&sTt[v*132 + rbase];  // 16B-aligned, conflict-free
        f32x4 ta = tvp[0], tb = tvp[1];
        float e = er[v];
        dA += ta * e;
        dB += tb * e;
      }
      short8 af;
      #pragma unroll
      for (int i=0;i<4;i++) af[i]   = f2bf(expm1t(fmaxf(dA[i], 0.f)));
      #pragma unroll
      for (int i=0;i<4;i++) af[4+i] = f2bf(expm1t(fmaxf(dB[i], 0.f)));
      short8 bf0, bf1;
      #pragma unroll
      for (int i=0;i<8;i++) {
        int row = (rbase + i)*34;
        bf0[i] = (short)sYb[row + fc];
        bf1[i] = (short)sYb[row + 16 + fc];
      }
      acc0 = __builtin_amdgcn_mfma_f32_16x16x32_bf16(af, bf0, acc0, 0, 0, 0);
      acc1 = __builtin_amdgcn_mfma_f32_16x16x32_bf16(af, bf1, acc1, 0, 0, 0);
    }
  }
  float* pb = part + (size_t)((s*nt + ty)*nsplit + split)*(N_E*32);
  #pragma unroll
  for (int r=0;r<4;r++) {
    pb[(size_t)(m0 + g*4 + r)*32 + fc]      = acc0[r];
    pb[(size_t)(m0 + g*4 + r)*32 + 16 + fc] = acc1[r];
  }
}

// ---------------- reduce nsplit partials + ysum + Wg + bias + ReLU ----------------
__global__ __launch_bounds__(256) void k_wg(const float* __restrict__ part,
                     const float* __restrict__ ysumb,
                     const float* __restrict__ Wgp, const float* __restrict__ Wga,
                     const float* __restrict__ bgp, const float* __restrict__ bga,
                     float* __restrict__ xop, float* __restrict__ xoa,
                     int layer, int tbase, int tstep, int nt, int nsplit) {
  __shared__ float sX[8*32];
  __shared__ float sWg[32*32];
  __shared__ float sBg[32];
  int s = blockIdx.z, ty = blockIdx.y;
  int t = tbase + ty*tstep;
  int m0 = blockIdx.x*8;
  const float* Wg = (s ? Wga : Wgp) + (size_t)layer*1024;
  const float* bg = (s ? bga : bgp) + layer*32;
  int tid = threadIdx.x;
  for (int i = tid; i < 1024; i += 256) sWg[i] = Wg[i];
  if (tid < 32) sBg[tid] = bg[tid];
  {
    int mm = tid >> 5, f = tid & 31;
    const float* p = part + (size_t)((s*nt + ty)*nsplit)*(N_E*32) + (size_t)(m0+mm)*32 + f;
    float a = ysumb[((size_t)s*nt + ty)*32 + f];
    for (int sp = 0; sp < nsplit; sp++) a += p[(size_t)sp*(N_E*32)];
    sX[mm*32+f] = a;
  }
  __syncthreads();
  int mm = tid >> 5, g = tid & 31;
  float a = sBg[g];
  #pragma unroll
  for (int f=0;f<32;f++) a += sX[mm*32+f]*sWg[f*32+g];
  (s ? xoa : xop)[((size_t)t*N_E + m0+mm)*32 + g] = fmaxf(a, 0.f);
}

// ---------------- fused gather + 6-layer MLP head ----------------
__global__ __launch_bounds__(64) void k_mlp(const int* __restrict__ info,
    const float* __restrict__ tf, const float* __restrict__ fpp, const float* __restrict__ fpa,
    const float* __restrict__ se, const float* __restrict__ ve,
    const float* __restrict__ W0, const float* __restrict__ b0,
    const float* __restrict__ W1, const float* __restrict__ b1,
    const float* __restrict__ W2, const float* __restrict__ b2,
    const float* __restrict__ W3, const float* __restrict__ b3,
    const float* __restrict__ W4, const float* __restrict__ b4,
    const float* __restrict__ W5, const float* __restrict__ b5,
    float* __restrict__ out) {
  int r = blockIdx.x*64 + threadIdx.x;
  int uid = info[r*4+0], eid = info[r*4+1], sid = info[r*4+2];
  float o0[64];
  #pragma unroll
  for (int g=0;g<64;g++) o0[g] = b0[g];
  for (int k=0;k<16;k++) {
    float v = tf[uid*16+k];
    #pragma unroll
    for (int g=0;g<64;g++) o0[g] = fmaf(W0[g*112+k], v, o0[g]);
  }
  for (int k=0;k<32;k++) {
    float v = 0.5f*(fpp[eid*32+k] + fpa[eid*32+k]);
    #pragma unroll
    for (int g=0;g<64;g++) o0[g] = fmaf(W0[g*112+16+k], v, o0[g]);
  }
  for (int k=0;k<32;k++) {
    float v = se[eid*32+k];
    #pragma unroll
    for (int g=0;g<64;g++) o0[g] = fmaf(W0[g*112+48+k], v, o0[g]);
  }
  for (int k=0;k<32;k++) {
    float v = ve[sid*32+k];
    #pragma unroll
    for (int g=0;g<64;g++) o0[g] = fmaf(W0[g*112+80+k], v, o0[g]);
  }
  #pragma unroll
  for (int g=0;g<64;g++) o0[g] = fmaxf(o0[g], 0.f);
  float o1[32];
  #pragma unroll
  for (int g=0;g<32;g++) {
    float a = b1[g];
    #pragma unroll
    for (int k=0;k<64;k++) a = fmaf(W1[g*64+k], o0[k], a);
    o1[g] = fmaxf(a, 0.f);
  }
  float o2[16];
  #pragma unroll
  for (int g=0;g<16;g++) {
    float a = b2[g];
    #pragma unroll
    for (int k=0;k<32;k++) a = fmaf(W2[g*32+k], o1[k], a);
    o2[g] = fmaxf(a, 0.f);
  }
  float o3[8];
  #pragma unroll
  for (int g=0;g<8;g++) {
    float a = b3[g];
    #pragma unroll
    for (int k=0;k<16;k++) a = fmaf(W3[g*16+k], o2[k], a);
    o3[g] = fmaxf(a, 0.f);
  }
  float o4[4];
  #pragma unroll
  for (int g=0;g<4;g++) {
    float a = b4[g];
    #pragma unroll
    for (int k=0;k<8;k++) a = fmaf(W4[g*8+k], o3[k], a);
    o4[g] = fmaxf(a, 0.f);
  }
  float o5 = b5[0];
  #pragma unroll
  for (int k=0;k<4;k++) o5 = fmaf(W5[k], o4[k], o5);
  out[r] = o5;
}

extern "C" void kernel_launch(void* const* d_in, const int* in_sizes, int n_in,
                              void* d_out, int out_size, void* d_ws, size_t ws_size,
                              hipStream_t stream) {
  (void)in_sizes; (void)n_in; (void)out_size;
  const float* edge    = (const float*)d_in[0];
  const float* loadx   = (const float*)d_in[1];
  const float* svcx    = (const float*)d_in[2];
  const float* tra     = (const float*)d_in[3];
  const int*   info    = (const int*)d_in[4];
  const int*   srv_attr= (const int*)d_in[5];
  const int*   svc_attr= (const int*)d_in[6];
  const float* usr_tab = (const float*)d_in[7];
  const float* srv_tab0= (const float*)d_in[8];
  const float* srv_lvl = (const float*)d_in[9];
  const float* svc_tab0= (const float*)d_in[10];
  const float* svc_lvl = (const float*)d_in[11];
  const float* Wih = (const float*)d_in[12];
  const float* Whh = (const float*)d_in[13];
  const float* bih = (const float*)d_in[14];
  const float* bhh = (const float*)d_in[15];
  const float* E1p = (const float*)d_in[16];
  const float* E2p = (const float*)d_in[17];
  const float* peWp= (const float*)d_in[18];
  const float* pebp= (const float*)d_in[19];
  const float* E1a = (const float*)d_in[20];
  const float* E2a = (const float*)d_in[21];
  const float* peWa= (const float*)d_in[22];
  const float* peba= (const float*)d_in[23];
  const float* prWp= (const float*)d_in[24];
  const float* prbp= (const float*)d_in[25];
  const float* prWa= (const float*)d_in[26];
  const float* prba= (const float*)d_in[27];
  const float* Wtp = (const float*)d_in[28];
  const float* btp = (const float*)d_in[29];
  const float* Wgp = (const float*)d_in[30];
  const float* bgp = (const float*)d_in[31];
  const float* Wta = (const float*)d_in[32];
  const float* bta = (const float*)d_in[33];
  const float* Wga = (const float*)d_in[34];
  const float* bga = (const float*)d_in[35];
  const float* qW0 = (const float*)d_in[36]; const float* qb0 = (const float*)d_in[37];
  const float* qW1 = (const float*)d_in[38]; const float* qb1 = (const float*)d_in[39];
  const float* qW2 = (const float*)d_in[40]; const float* qb2 = (const float*)d_in[41];
  const float* qW3 = (const float*)d_in[42]; const float* qb3 = (const float*)d_in[43];
  const float* qW4 = (const float*)d_in[44]; const float* qb4 = (const float*)d_in[45];
  const float* qW5 = (const float*)d_in[46]; const float* qb5 = (const float*)d_in[47];
  float* out = (float*)d_out;

  // workspace layout (floats); part sized from remaining ws
  float* ws = (float*)d_ws;
  size_t off = 0;
  float* srv_emb  = ws + off; off += (size_t)N_E*32;
  float* svc_emb  = ws + off; off += (size_t)N_SVC*32;
  float* tra_feat = ws + off; off += (size_t)N_U*16;
  float* epb      = ws + off; off += 2ull*KT*N_E*8;     // [s][t][n][8]
  float* Ttb      = ws + off; off += 2ull*TSTR;         // [s][t][8][n] transposed
  float* Zb       = ws + off; off += 2ull*KT*N_E;       // 1/softmax-denominator
  float* ysumb    = ws + off; off += 2ull*KT*32;        // per-(s,t) colsum of y'
  float* x0b      = ws + off; off += 2ull*STRX;
  float* xAb      = ws + off; off += 2ull*STRX;
  unsigned short* ybf = (unsigned short*)(ws + off); off += (2ull*YSTR)/2;  // bf16 y'
  float* part     = ws + off;                           // rest of ws

  size_t slab = (size_t)N_E*32;                          // 65536 floats
  size_t avail_floats = (ws_size/4 > off) ? (ws_size/4 - off) : 0;
  int cap = (int)(avail_floats / slab);                  // total part slabs available

  float* epp = epb;              float* epa = epb + (size_t)KT*N_E*8;
  float* Ttp = Ttb;              float* Tta = Ttb + (size_t)TSTR;
  unsigned short* ybp = ybf;     unsigned short* yba = ybf + (size_t)YSTR;
  // stats partials alias onto `part`: consumed by k_zinv before first k_mixm writes it
  float* partC = part;           // needs 8 slabs (2 MB)

  k_embed<<<384,256,0,stream>>>(srv_attr, svc_attr, srv_tab0, srv_lvl, svc_tab0, svc_lvl, srv_emb, svc_emb);
  k_lstm <<<256,256,0,stream>>>(usr_tab, tra, Wih, Whh, bih, bhh, tra_feat);
  k_pe   <<<1408,256,0,stream>>>(edge, peWp, pebp, peWa, peba, epp, epa);
  k_T    <<<22,256,0,stream>>>(epp, epa, E1p, E2p, E1a, E2a, Ttp, Tta);
  k_stats<<<dim3(64,11,2),256,0,stream>>>(Ttp, Tta, epp, epa, partC);
  k_zinv <<<176,256,0,stream>>>(partC, Zb);
  k_proj <<<8192,256,0,stream>>>(loadx, svcx, prWp, prbp, prWa, prba, x0b, x0b + STRX);

  // per-layer active time sets (backward-propagated from t=15 output)
  const int Ldd[4]   = {1, 2, 1, 2};
  const int Ltb[4]   = {5, 9, 11, 15};
  const int Lts[4]   = {1, 1, 2, 1};
  const int Lnt[4]   = {11, 7, 3, 1};
  int Lsp[4]         = {4, 4, 8, 16};        // n-splits (occupancy vs part traffic)
  for (int i = 0; i < 4; i++)
    while (Lsp[i] > 1 && 2*Lnt[i]*Lsp[i] > cap) Lsp[i] >>= 1;

  float* xin = x0b;
  float* xout = xAb;
  for (int i = 0; i < 4; i++) {
    k_conv<<<dim3(256, Lnt[i], 2), 256, 0, stream>>>(
        xin, xin + STRX, Wtp, Wta, btp, bta, Zb, ybp, yba, i, Ldd[i], Ltb[i], Lts[i]);
    k_ysum<<<dim3(Lnt[i], 2), 256, 0, stream>>>(ybp, yba, ysumb, Ltb[i], Lts[i], Lnt[i]);
    k_mixm<<<dim3(32*Lsp[i], Lnt[i], 2), 256, 0, stream>>>(
        Ttp, Tta, epp, epa, ybp, yba, part, Ltb[i], Lts[i], Lnt[i], Lsp[i]);
    k_wg<<<dim3(256, Lnt[i], 2), 256, 0, stream>>>(
        part, ysumb, Wgp, Wga, bgp, bga, xout, xout + STRX, i, Ltb[i], Lts[i], Lnt[i], Lsp[i]);
    float* tmp = xin; xin = xout; xout = tmp;
  }
  // final stream features at t=15 live in xin
  const float* fpp = xin + (size_t)15*N_E*32;
  const float* fpa = xin + STRX + (size_t)15*N_E*32;

  k_mlp<<<128,64,0,stream>>>(info, tra_feat, fpp, fpa, srv_emb, svc_emb,
                             qW0, qb0, qW1, qb1, qW2, qb2, qW3, qb3, qW4, qb4, qW5, qb5, out);
}

// Round 8
// 641.570 us; speedup vs baseline: 1.0332x; 1.0332x over previous
//
#include <hip/hip_runtime.h>
#include <math.h>

#define N_E 2048
#define N_U 4096
#define N_SVC 1024
#define KT 16
#define STRX (KT*N_E*32)   // per-stream x buffer stride (floats)
#define YSTR (KT*N_E*32)   // per-stream y buffer stride (shorts)
#define TSTR (KT*8*N_E)    // per-stream T^T stride (floats)

typedef __attribute__((ext_vector_type(8))) short short8;   // 8 bf16 (4 VGPRs)
typedef __attribute__((ext_vector_type(4))) float f32x4;

__device__ __forceinline__ float sigf(float x){ return 1.0f/(1.0f+__expf(-x)); }
__device__ __forceinline__ float tanhfast(float x){ return 1.0f - 2.0f/(__expf(2.0f*x)+1.0f); }
__device__ __forceinline__ short f2bf(float f){
  union { float f; unsigned u; } x; x.f = f;
  unsigned r = x.u + 0x7FFFu + ((x.u >> 16) & 1u);
  return (short)(r >> 16);
}
__device__ __forceinline__ float bf2f(unsigned short u){
  union { unsigned u; float f; } x; x.u = ((unsigned)u) << 16; return x.f;
}
// expm1 via 4-term Taylor: rel err <1e-5 for d in [0, 0.5]; d here is ~<0.05
__device__ __forceinline__ float expm1t(float d){
  float t = fmaf(d, 1.f/24.f, 1.f/6.f);
  t = fmaf(d, t, 0.5f);
  t = fmaf(d, t, 1.f);
  return d*t;
}

// ---------------- embeddings: srv_emb (2048x32), svc_emb (1024x32) ----------------
__global__ void k_embed(const int* __restrict__ srv_attr, const int* __restrict__ svc_attr,
                        const float* __restrict__ srv_tab0, const float* __restrict__ srv_lvl,
                        const float* __restrict__ svc_tab0, const float* __restrict__ svc_lvl,
                        float* __restrict__ srv_emb, float* __restrict__ svc_emb) {
  int idx = blockIdx.x*256 + threadIdx.x;       // (2048+1024) rows * 32 cols
  int r = idx >> 5, c = idx & 31;
  int seg = c >> 3, cc = c & 7;
  if (r < N_E) {
    int a = srv_attr[r*4 + seg];
    srv_emb[r*32 + c] = (seg==0) ? srv_tab0[a*8+cc] : srv_lvl[((seg-1)*10 + a)*8 + cc];
  } else {
    int r2 = r - N_E;
    if (r2 < N_SVC) {
      int a = svc_attr[r2*4 + seg];
      svc_emb[r2*32 + c] = (seg==0) ? svc_tab0[a*8+cc] : svc_lvl[((seg-1)*10 + a)*8 + cc];
    }
  }
}

// ---------------- LSTM: 16 lanes per user, lane j owns hidden unit j ----------------
__global__ __launch_bounds__(256) void k_lstm(const float* __restrict__ usr_tab, const float* __restrict__ tra,
                       const float* __restrict__ Wih, const float* __restrict__ Whh,
                       const float* __restrict__ bih, const float* __restrict__ bhh,
                       float* __restrict__ tra_feat) {
  __shared__ float sWih[64*12];
  __shared__ float sWhh[64*16];
  __shared__ float sB[64];
  int tid = threadIdx.x;
  for (int i = tid; i < 64*12; i += 256) sWih[i] = Wih[i];
  for (int i = tid; i < 64*16; i += 256) sWhh[i] = Whh[i];
  if (tid < 64) sB[tid] = bih[tid] + bhh[tid];
  __syncthreads();
  int j  = tid & 15;
  int u  = blockIdx.x*16 + (tid >> 4);
  float xe[8];
  #pragma unroll
  for (int k=0;k<8;k++) xe[k] = usr_tab[u*8+k];
  float h = 0.f, c = 0.f;
  for (int t=0;t<KT;t++) {
    float gi = sB[j], gf = sB[16+j], gg = sB[32+j], go = sB[48+j];
    #pragma unroll
    for (int k=0;k<8;k++) {
      float v = xe[k];
      gi += sWih[j*12+k]*v;      gf += sWih[(16+j)*12+k]*v;
      gg += sWih[(32+j)*12+k]*v; go += sWih[(48+j)*12+k]*v;
    }
    #pragma unroll
    for (int k=0;k<4;k++) {
      float v = tra[((size_t)t*N_U + u)*4 + k];
      gi += sWih[j*12+8+k]*v;      gf += sWih[(16+j)*12+8+k]*v;
      gg += sWih[(32+j)*12+8+k]*v; go += sWih[(48+j)*12+8+k]*v;
    }
    #pragma unroll
    for (int jj=0;jj<16;jj++) {
      float hv = __shfl(h, jj, 16);
      gi += sWhh[j*16+jj]*hv;      gf += sWhh[(16+j)*16+jj]*hv;
      gg += sWhh[(32+j)*16+jj]*hv; go += sWhh[(48+j)*16+jj]*hv;
    }
    c = sigf(gf)*c + sigf(gi)*tanhfast(gg);
    h = sigf(go)*tanhfast(c);
  }
  tra_feat[u*16 + j] = h;
}

// ---------------- ep/ea = edge @ peW^T + b : only t in [5,15] ----------------
__global__ void k_pe(const float* __restrict__ edge,
                     const float* __restrict__ Wp, const float* __restrict__ bp,
                     const float* __restrict__ Wa, const float* __restrict__ ba,
                     float* __restrict__ ep, float* __restrict__ ea) {
  int idx = blockIdx.x*256 + threadIdx.x;        // s(2)*t(11)*n(2048)*c(8) = 360448
  int c = idx & 7; int rest = idx >> 3;
  int n = rest & 2047; rest >>= 11;              // rest in [0, 22)
  int t = 5 + (rest % 11); int s = rest / 11;
  const float* W = s ? Wa : Wp; const float* b = s ? ba : bp;
  const float* e = edge + ((size_t)t*N_E + n)*11;
  float acc = b[c];
  #pragma unroll
  for (int k=0;k<11;k++) acc += e[k]*W[c*11+k];
  (s ? ea : ep)[((size_t)t*N_E + n)*8 + c] = acc;
}

// ---------------- Tt[t][v][n] = (ep[t] @ (E2[t].E1))^T : only t in [5,15] ----------------
__global__ void k_T(const float* __restrict__ epp, const float* __restrict__ epa,
                    const float* __restrict__ E1p, const float* __restrict__ E2p,
                    const float* __restrict__ E1a, const float* __restrict__ E2a,
                    float* __restrict__ Ttp, float* __restrict__ Tta) {
  __shared__ float sM[64];
  int s = blockIdx.x / 11, t = 5 + blockIdx.x % 11;
  const float* E1 = s ? E1a : E1p;
  const float* E2 = s ? E2a : E2p;
  const float* ep = (s ? epa : epp) + (size_t)t*N_E*8;
  float* Tt = (s ? Tta : Ttp) + (size_t)t*8*N_E;
  int tid = threadIdx.x;
  if (tid < 64) {
    int u = tid >> 3, v = tid & 7;
    float m = 0.f;
    #pragma unroll
    for (int o=0;o<8;o++) m += E2[t*8+o]*E1[(o*8+u)*8+v];
    sM[u*8+v] = m;
  }
  __syncthreads();
  for (int i = tid; i < N_E; i += 256) {
    float e[8];
    const float4* g4 = (const float4*)(ep + (size_t)i*8);
    float4 a = g4[0], b = g4[1];
    e[0]=a.x; e[1]=a.y; e[2]=a.z; e[3]=a.w; e[4]=b.x; e[5]=b.y; e[6]=b.z; e[7]=b.w;
    #pragma unroll
    for (int v=0;v<8;v++) {
      float acc = 0.f;
      #pragma unroll
      for (int u=0;u<8;u++) acc += e[u]*sM[u*8+v];
      Tt[(size_t)v*N_E + i] = acc;   // coalesced across lanes
    }
  }
}

// --------- softmax row partials: partC[s,t,sp,n] = sum_{m in split sp} exp(relu(T[n].ep[m])) ---------
__global__ __launch_bounds__(256) void k_stats(const float* __restrict__ Ttp, const float* __restrict__ Tta,
                        const float* __restrict__ epp, const float* __restrict__ epa,
                        float* __restrict__ partC) {
  __shared__ float sE[256*8];   // 8 KiB
  int s = blockIdx.z, t = 5 + blockIdx.y;
  int ntile = blockIdx.x & 7, sp = blockIdx.x >> 3;
  int n = ntile*256 + threadIdx.x;
  const float* Tt = (s ? Tta : Ttp) + (size_t)t*8*N_E;
  const float* E = (s ? epa : epp) + (size_t)t*N_E*8;
  int tid = threadIdx.x;
  float tr[8];
  #pragma unroll
  for (int v=0;v<8;v++) tr[v] = Tt[(size_t)v*N_E + n];   // coalesced
  int m0 = sp*256;
  {
    const float4* ge = (const float4*)(E + (size_t)m0*8);
    float4* se = (float4*)sE;
    for (int i = tid; i < 512; i += 256) se[i] = ge[i];
  }
  __syncthreads();
  float psum = 0.f;
  #pragma unroll 4
  for (int m = 0; m < 256; m++) {
    float d = 0.f;
    #pragma unroll
    for (int v=0;v<8;v++) d = fmaf(sE[m*8+v], tr[v], d);
    psum += __expf(fmaxf(d, 0.f));
  }
  partC[(((size_t)s*KT + t)*8 + sp)*N_E + n] = psum;
}

// ---------------- Zinv = 1 / (sum of 8 partials), t in [5,15] ----------------
__global__ void k_zinv(const float* __restrict__ partC, float* __restrict__ Z) {
  int i = blockIdx.x*256 + threadIdx.x;   // 2*11*2048 = 45056
  int n = i & 2047; int stp = i >> 11;    // [0,22)
  int s = stp / 11, t = 5 + stp % 11;
  float a = 0.f;
  #pragma unroll
  for (int sp=0;sp<8;sp++) a += partC[(((size_t)s*KT + t)*8 + sp)*N_E + n];
  Z[((size_t)s*KT + t)*N_E + n] = 1.0f/a;
}

// ---------------- x0 = proj(load / svc_tot) : (16,2048,32) x2 ----------------
__global__ void k_proj(const float* __restrict__ loadx, const float* __restrict__ svcx,
                       const float* __restrict__ Wp, const float* __restrict__ bp,
                       const float* __restrict__ Wa, const float* __restrict__ ba,
                       float* __restrict__ x0p, float* __restrict__ x0a) {
  int idx = blockIdx.x*256 + threadIdx.x;        // s t n g : 21 bits
  int g = idx & 31; int rest = idx >> 5;
  int n = rest & 2047; rest >>= 11; int t = rest & 15; int s = rest >> 4;
  const float* in = (s ? svcx : loadx) + ((size_t)t*N_E + n)*3;
  const float* W = s ? Wa : Wp; const float* b = s ? ba : bp;
  float acc = b[g];
  #pragma unroll
  for (int c=0;c<3;c++) acc += in[c]*W[g*3+c];
  (s ? x0a : x0p)[((size_t)t*N_E + n)*32 + g] = acc;
}

// ------- dilated causal conv (kernel 3) + ReLU, scaled by Zinv[n], output bf16 -------
__global__ __launch_bounds__(256) void k_conv(const float* __restrict__ xp, const float* __restrict__ xa,
                       const float* __restrict__ Wtp, const float* __restrict__ Wta,
                       const float* __restrict__ btp, const float* __restrict__ bta,
                       const float* __restrict__ Zg,
                       unsigned short* __restrict__ yp, unsigned short* __restrict__ ya,
                       int layer, int dd, int tbase, int tstep) {
  __shared__ float sW[3*32*32];
  __shared__ float sX[8][3][32];
  int s = blockIdx.z;
  int t = tbase + blockIdx.y*tstep;
  const float* x  = s ? xa : xp;
  const float* Wt = (s ? Wta : Wtp) + (size_t)layer*3*32*32;
  const float* bt = (s ? bta : btp) + layer*32;
  unsigned short* y = s ? ya : yp;
  int tid = threadIdx.x;
  for (int i = tid; i < 3*32*32; i += 256) sW[i] = Wt[i];
  int n0 = blockIdx.x*8;
  for (int i = tid; i < 768; i += 256) {
    int f = i & 31; int nn = (i>>5)&7; int j = i >> 8;
    int tt = t - (2-j)*dd;
    sX[nn][j][f] = (tt >= 0) ? x[((size_t)tt*N_E + n0+nn)*32 + f] : 0.f;
  }
  __syncthreads();
  int g = tid & 31, nn = tid >> 5;
  float acc = bt[g];
  #pragma unroll
  for (int j=0;j<3;j++)
    #pragma unroll
    for (int f=0;f<32;f++) acc += sX[nn][j][f]*sW[(j*32+f)*32+g];
  float zi = Zg[((size_t)s*KT + t)*N_E + n0+nn];
  y[((size_t)t*N_E + n0+nn)*32 + g] = (unsigned short)f2bf(fmaxf(acc, 0.f)*zi);
}

// ---------------- ysum[s,ty,f] = sum_n y'[n,f] (f32 colsum of bf16 y') ----------------
__global__ __launch_bounds__(256) void k_ysum(const unsigned short* __restrict__ yp,
                       const unsigned short* __restrict__ ya,
                       float* __restrict__ ysumb, int tbase, int tstep, int nt) {
  __shared__ float red[256];
  int ty = blockIdx.x, s = blockIdx.y;
  int t = tbase + ty*tstep;
  const unsigned short* y = (s ? ya : yp) + (size_t)t*N_E*32;
  int tid = threadIdx.x;
  int f = tid & 31, sl = tid >> 5;
  float a = 0.f;
  for (int nn = sl*256; nn < sl*256 + 256; nn++) a += bf2f(y[(size_t)nn*32 + f]);
  red[tid] = a;
  __syncthreads();
  if (tid < 32) {
    float acc = 0.f;
    #pragma unroll
    for (int k=0;k<8;k++) acc += red[tid + 32*k];
    ysumb[((size_t)s*nt + ty)*32 + tid] = acc;
  }
}

// --------- MFMA mixing: part[m,f] = sum_n q[n,m] * y'[n,f],  q = expm1(relu(T[n].ep[m])) ---------
// T^T and bf16 Y precomputed globally; per-chunk reg-staged pipeline (issue next chunk's
// 3 float4 loads before computing current -> HBM latency hidden under compute).
__global__ __launch_bounds__(256) void k_mixm(const float* __restrict__ Ttp, const float* __restrict__ Tta,
                      const float* __restrict__ epp, const float* __restrict__ epa,
                      const unsigned short* __restrict__ ybp, const unsigned short* __restrict__ yba,
                      float* __restrict__ part,
                      int tbase, int tstep, int nt, int nsplit) {
  __shared__ float sTt[8*132];             // 4.1 KiB, T^T chunk, pad 132
  __shared__ unsigned short sYb[128*34];   // 8.5 KiB, bf16 y chunk, pad 34
  int s = blockIdx.z, ty = blockIdx.y;
  int t = tbase + ty*tstep;
  int mtile = blockIdx.x & 31, split = blockIdx.x >> 5;
  int tid = threadIdx.x;
  int w = tid >> 6, lane = tid & 63;
  int g = lane >> 4, fc = lane & 15;
  int m0 = mtile*64 + w*16;
  const float* Tt = (s ? Tta : Ttp) + (size_t)t*8*N_E;
  const float* ep = (s ? epa : epp) + (size_t)t*N_E*8;
  const unsigned short* yb = (s ? yba : ybp) + (size_t)t*N_E*32;
  float er[8];
  {
    const float4* gep = (const float4*)(ep + (size_t)(m0 + fc)*8);
    float4 a = gep[0], b = gep[1];
    er[0]=a.x; er[1]=a.y; er[2]=a.z; er[3]=a.w;
    er[4]=b.x; er[5]=b.y; er[6]=b.z; er[7]=b.w;
  }
  f32x4 acc0 = {0.f,0.f,0.f,0.f}, acc1 = {0.f,0.f,0.f,0.f};
  int n0 = split*(N_E/nsplit), n1 = n0 + (N_E/nsplit);   // multiples of 128
  int tv = tid >> 5, tc = tid & 31;       // T-stage coords: row v, col-quad
  float4 tReg, yR0, yR1;
  {
    tReg = *(const float4*)(Tt + (size_t)tv*N_E + n0 + tc*4);
    const float4* gy = (const float4*)(yb + (size_t)n0*32);
    yR0 = gy[tid]; yR1 = gy[tid + 256];
  }
  for (int c0 = n0; c0 < n1; c0 += 128) {
    __syncthreads();
    // write staged regs to LDS
    *(float4*)&sTt[tv*132 + tc*4] = tReg;
    {
      union { float4 f; unsigned u[4]; } cv;
      cv.f = yR0;
      unsigned* d0 = (unsigned*)&sYb[(tid>>2)*34 + (tid&3)*8];
      d0[0]=cv.u[0]; d0[1]=cv.u[1]; d0[2]=cv.u[2]; d0[3]=cv.u[3];
      cv.f = yR1;
      unsigned* d1 = (unsigned*)&sYb[(64 + (tid>>2))*34 + (tid&3)*8];
      d1[0]=cv.u[0]; d1[1]=cv.u[1]; d1[2]=cv.u[2]; d1[3]=cv.u[3];
    }
    __syncthreads();
    if (c0 + 128 < n1) {   // issue next chunk's loads; latency hides under compute below
      tReg = *(const float4*)(Tt + (size_t)tv*N_E + (c0+128) + tc*4);
      const float4* gy = (const float4*)(yb + (size_t)(c0+128)*32);
      yR0 = gy[tid]; yR1 = gy[tid + 256];
    }
    #pragma unroll
    for (int sub = 0; sub < 4; sub++) {
      int rbase = sub*32 + g*8;
      f32x4 dA = {0.f,0.f,0.f,0.f}, dB = {0.f,0.f,0.f,0.f};
      #pragma unroll
      for (int v=0; v<8; v++) {
        const f32x4* tvp = (const f32x4*)&sTt[v*132 + rbase];  // 16B-aligned, conflict-free
        f32x4 ta = tvp[0], tb = tvp[1];
        float e = er[v];
        dA += ta * e;
        dB += tb * e;
      }
      short8 af;
      #pragma unroll
      for (int i=0;i<4;i++) af[i]   = f2bf(expm1t(fmaxf(dA[i], 0.f)));
      #pragma unroll
      for (int i=0;i<4;i++) af[4+i] = f2bf(expm1t(fmaxf(dB[i], 0.f)));
      short8 bf0, bf1;
      #pragma unroll
      for (int i=0;i<8;i++) {
        int row = (rbase + i)*34;
        bf0[i] = (short)sYb[row + fc];
        bf1[i] = (short)sYb[row + 16 + fc];
      }
      acc0 = __builtin_amdgcn_mfma_f32_16x16x32_bf16(af, bf0, acc0, 0, 0, 0);
      acc1 = __builtin_amdgcn_mfma_f32_16x16x32_bf16(af, bf1, acc1, 0, 0, 0);
    }
  }
  float* pb = part + (size_t)((s*nt + ty)*nsplit + split)*(N_E*32);
  #pragma unroll
  for (int r=0;r<4;r++) {
    pb[(size_t)(m0 + g*4 + r)*32 + fc]      = acc0[r];
    pb[(size_t)(m0 + g*4 + r)*32 + 16 + fc] = acc1[r];
  }
}

// ---------------- reduce nsplit partials + ysum + Wg + bias + ReLU ----------------
__global__ __launch_bounds__(256) void k_wg(const float* __restrict__ part,
                     const float* __restrict__ ysumb,
                     const float* __restrict__ Wgp, const float* __restrict__ Wga,
                     const float* __restrict__ bgp, const float* __restrict__ bga,
                     float* __restrict__ xop, float* __restrict__ xoa,
                     int layer, int tbase, int tstep, int nt, int nsplit) {
  __shared__ float sX[8*32];
  __shared__ float sWg[32*32];
  __shared__ float sBg[32];
  int s = blockIdx.z, ty = blockIdx.y;
  int t = tbase + ty*tstep;
  int m0 = blockIdx.x*8;
  const float* Wg = (s ? Wga : Wgp) + (size_t)layer*1024;
  const float* bg = (s ? bga : bgp) + layer*32;
  int tid = threadIdx.x;
  for (int i = tid; i < 1024; i += 256) sWg[i] = Wg[i];
  if (tid < 32) sBg[tid] = bg[tid];
  {
    int mm = tid >> 5, f = tid & 31;
    const float* p = part + (size_t)((s*nt + ty)*nsplit)*(N_E*32) + (size_t)(m0+mm)*32 + f;
    float a = ysumb[((size_t)s*nt + ty)*32 + f];
    for (int sp = 0; sp < nsplit; sp++) a += p[(size_t)sp*(N_E*32)];
    sX[mm*32+f] = a;
  }
  __syncthreads();
  int mm = tid >> 5, g = tid & 31;
  float a = sBg[g];
  #pragma unroll
  for (int f=0;f<32;f++) a += sX[mm*32+f]*sWg[f*32+g];
  (s ? xoa : xop)[((size_t)t*N_E + m0+mm)*32 + g] = fmaxf(a, 0.f);
}

// ---------------- fused gather + 6-layer MLP head, LDS-resident transposed weights ----------------
__global__ __launch_bounds__(64) void k_mlp(const int* __restrict__ info,
    const float* __restrict__ tf, const float* __restrict__ fpp, const float* __restrict__ fpa,
    const float* __restrict__ se, const float* __restrict__ ve,
    const float* __restrict__ W0, const float* __restrict__ b0,
    const float* __restrict__ W1, const float* __restrict__ b1,
    const float* __restrict__ W2, const float* __restrict__ b2,
    const float* __restrict__ W3, const float* __restrict__ b3,
    const float* __restrict__ W4, const float* __restrict__ b4,
    const float* __restrict__ W5, const float* __restrict__ b5,
    float* __restrict__ out) {
  __shared__ float sW0t[112*64];   // [k][g] transposed, 28 KiB
  __shared__ float sW1t[64*32];
  __shared__ float sW2t[32*16];
  __shared__ float sW3t[16*8];
  __shared__ float sW4t[8*4];
  __shared__ float sW5[4];
  __shared__ float sB0[64];
  __shared__ float sB1[32];
  __shared__ float sB2[16];
  __shared__ float sB3[8];
  __shared__ float sB4[4];
  __shared__ float sB5[1];
  int tid = threadIdx.x;
  // stage transposed weights (64 threads)
  for (int i = tid; i < 1792; i += 64) {        // W0: 64x112 floats, f4 along k
    float4 v = ((const float4*)W0)[i];
    int g = i / 28, kq = (i % 28)*4;
    sW0t[(kq+0)*64+g]=v.x; sW0t[(kq+1)*64+g]=v.y; sW0t[(kq+2)*64+g]=v.z; sW0t[(kq+3)*64+g]=v.w;
  }
  for (int i = tid; i < 2048; i += 64) sW1t[(i&63)*32 + (i>>6)] = W1[i];   // W1: 32x64
  for (int i = tid; i < 512; i += 64)  sW2t[(i&31)*16 + (i>>5)] = W2[i];   // W2: 16x32
  for (int i = tid; i < 128; i += 64)  sW3t[(i&15)*8  + (i>>4)] = W3[i];   // W3: 8x16
  if (tid < 32) sW4t[(tid&7)*4 + (tid>>3)] = W4[tid];                      // W4: 4x8
  if (tid < 4)  sW5[tid] = W5[tid];
  if (tid < 64) sB0[tid] = b0[tid];
  if (tid < 32) sB1[tid] = b1[tid];
  if (tid < 16) sB2[tid] = b2[tid];
  if (tid < 8)  sB3[tid] = b3[tid];
  if (tid < 4)  sB4[tid] = b4[tid];
  if (tid == 0) sB5[0] = b5[0];
  __syncthreads();

  int r = blockIdx.x*64 + tid;
  int4 ifo = ((const int4*)info)[r];
  int uid = ifo.x, eid = ifo.y, sid = ifo.z;

  f32x4 o0v[16];
  #pragma unroll
  for (int gq=0;gq<16;gq++) {
    o0v[gq][0]=sB0[gq*4]; o0v[gq][1]=sB0[gq*4+1]; o0v[gq][2]=sB0[gq*4+2]; o0v[gq][3]=sB0[gq*4+3];
  }
  // k 0..15: tra_feat
  {
    const float4* p = (const float4*)(tf + (size_t)uid*16);
    #pragma unroll
    for (int q=0;q<4;q++) {
      float4 v4 = p[q];
      #pragma unroll
      for (int j=0;j<4;j++) {
        float v = (&v4.x)[j];
        const f32x4* wc = (const f32x4*)&sW0t[(q*4+j)*64];
        #pragma unroll
        for (int gq=0;gq<16;gq++) o0v[gq] += wc[gq]*v;
      }
    }
  }
  // k 16..47: srv_fea = 0.5*(fpp+fpa)
  {
    const float4* pp = (const float4*)(fpp + (size_t)eid*32);
    const float4* pa = (const float4*)(fpa + (size_t)eid*32);
    #pragma unroll
    for (int q=0;q<8;q++) {
      float4 a4 = pp[q], b4 = pa[q];
      #pragma unroll
      for (int j=0;j<4;j++) {
        float v = 0.5f*((&a4.x)[j] + (&b4.x)[j]);
        const f32x4* wc = (const f32x4*)&sW0t[(16+q*4+j)*64];
        #pragma unroll
        for (int gq=0;gq<16;gq++) o0v[gq] += wc[gq]*v;
      }
    }
  }
  // k 48..79: srv_emb
  {
    const float4* p = (const float4*)(se + (size_t)eid*32);
    #pragma unroll
    for (int q=0;q<8;q++) {
      float4 v4 = p[q];
      #pragma unroll
      for (int j=0;j<4;j++) {
        float v = (&v4.x)[j];
        const f32x4* wc = (const f32x4*)&sW0t[(48+q*4+j)*64];
        #pragma unroll
        for (int gq=0;gq<16;gq++) o0v[gq] += wc[gq]*v;
      }
    }
  }
  // k 80..111: svc_emb
  {
    const float4* p = (const float4*)(ve + (size_t)sid*32);
    #pragma unroll
    for (int q=0;q<8;q++) {
      float4 v4 = p[q];
      #pragma unroll
      for (int j=0;j<4;j++) {
        float v = (&v4.x)[j];
        const f32x4* wc = (const f32x4*)&sW0t[(80+q*4+j)*64];
        #pragma unroll
        for (int gq=0;gq<16;gq++) o0v[gq] += wc[gq]*v;
      }
    }
  }
  #pragma unroll
  for (int gq=0;gq<16;gq++) {
    #pragma unroll
    for (int j=0;j<4;j++) o0v[gq][j] = fmaxf(o0v[gq][j], 0.f);
  }
  // layer 1: 64 -> 32
  f32x4 o1v[8];
  #pragma unroll
  for (int gq=0;gq<8;gq++) {
    o1v[gq][0]=sB1[gq*4]; o1v[gq][1]=sB1[gq*4+1]; o1v[gq][2]=sB1[gq*4+2]; o1v[gq][3]=sB1[gq*4+3];
  }
  #pragma unroll
  for (int k=0;k<64;k++) {
    float v = o0v[k>>2][k&3];
    const f32x4* wc = (const f32x4*)&sW1t[k*32];
    #pragma unroll
    for (int gq=0;gq<8;gq++) o1v[gq] += wc[gq]*v;
  }
  #pragma unroll
  for (int gq=0;gq<8;gq++) {
    #pragma unroll
    for (int j=0;j<4;j++) o1v[gq][j] = fmaxf(o1v[gq][j], 0.f);
  }
  // layer 2: 32 -> 16
  float o2[16];
  #pragma unroll
  for (int g=0;g<16;g++) o2[g] = sB2[g];
  #pragma unroll
  for (int k=0;k<32;k++) {
    float v = o1v[k>>2][k&3];
    #pragma unroll
    for (int g=0;g<16;g++) o2[g] = fmaf(sW2t[k*16+g], v, o2[g]);
  }
  #pragma unroll
  for (int g=0;g<16;g++) o2[g] = fmaxf(o2[g], 0.f);
  // layer 3: 16 -> 8
  float o3[8];
  #pragma unroll
  for (int g=0;g<8;g++) o3[g] = sB3[g];
  #pragma unroll
  for (int k=0;k<16;k++) {
    float v = o2[k];
    #pragma unroll
    for (int g=0;g<8;g++) o3[g] = fmaf(sW3t[k*8+g], v, o3[g]);
  }
  #pragma unroll
  for (int g=0;g<8;g++) o3[g] = fmaxf(o3[g], 0.f);
  // layer 4: 8 -> 4
  float o4[4];
  #pragma unroll
  for (int g=0;g<4;g++) o4[g] = sB4[g];
  #pragma unroll
  for (int k=0;k<8;k++) {
    float v = o3[k];
    #pragma unroll
    for (int g=0;g<4;g++) o4[g] = fmaf(sW4t[k*4+g], v, o4[g]);
  }
  #pragma unroll
  for (int g=0;g<4;g++) o4[g] = fmaxf(o4[g], 0.f);
  // layer 5: 4 -> 1
  float o5 = sB5[0];
  #pragma unroll
  for (int k=0;k<4;k++) o5 = fmaf(sW5[k], o4[k], o5);
  out[r] = o5;
}

extern "C" void kernel_launch(void* const* d_in, const int* in_sizes, int n_in,
                              void* d_out, int out_size, void* d_ws, size_t ws_size,
                              hipStream_t stream) {
  (void)in_sizes; (void)n_in; (void)out_size;
  const float* edge    = (const float*)d_in[0];
  const float* loadx   = (const float*)d_in[1];
  const float* svcx    = (const float*)d_in[2];
  const float* tra     = (const float*)d_in[3];
  const int*   info    = (const int*)d_in[4];
  const int*   srv_attr= (const int*)d_in[5];
  const int*   svc_attr= (const int*)d_in[6];
  const float* usr_tab = (const float*)d_in[7];
  const float* srv_tab0= (const float*)d_in[8];
  const float* srv_lvl = (const float*)d_in[9];
  const float* svc_tab0= (const float*)d_in[10];
  const float* svc_lvl = (const float*)d_in[11];
  const float* Wih = (const float*)d_in[12];
  const float* Whh = (const float*)d_in[13];
  const float* bih = (const float*)d_in[14];
  const float* bhh = (const float*)d_in[15];
  const float* E1p = (const float*)d_in[16];
  const float* E2p = (const float*)d_in[17];
  const float* peWp= (const float*)d_in[18];
  const float* pebp= (const float*)d_in[19];
  const float* E1a = (const float*)d_in[20];
  const float* E2a = (const float*)d_in[21];
  const float* peWa= (const float*)d_in[22];
  const float* peba= (const float*)d_in[23];
  const float* prWp= (const float*)d_in[24];
  const float* prbp= (const float*)d_in[25];
  const float* prWa= (const float*)d_in[26];
  const float* prba= (const float*)d_in[27];
  const float* Wtp = (const float*)d_in[28];
  const float* btp = (const float*)d_in[29];
  const float* Wgp = (const float*)d_in[30];
  const float* bgp = (const float*)d_in[31];
  const float* Wta = (const float*)d_in[32];
  const float* bta = (const float*)d_in[33];
  const float* Wga = (const float*)d_in[34];
  const float* bga = (const float*)d_in[35];
  const float* qW0 = (const float*)d_in[36]; const float* qb0 = (const float*)d_in[37];
  const float* qW1 = (const float*)d_in[38]; const float* qb1 = (const float*)d_in[39];
  const float* qW2 = (const float*)d_in[40]; const float* qb2 = (const float*)d_in[41];
  const float* qW3 = (const float*)d_in[42]; const float* qb3 = (const float*)d_in[43];
  const float* qW4 = (const float*)d_in[44]; const float* qb4 = (const float*)d_in[45];
  const float* qW5 = (const float*)d_in[46]; const float* qb5 = (const float*)d_in[47];
  float* out = (float*)d_out;

  // workspace layout (floats); part sized from remaining ws
  float* ws = (float*)d_ws;
  size_t off = 0;
  float* srv_emb  = ws + off; off += (size_t)N_E*32;
  float* svc_emb  = ws + off; off += (size_t)N_SVC*32;
  float* tra_feat = ws + off; off += (size_t)N_U*16;
  float* epb      = ws + off; off += 2ull*KT*N_E*8;     // [s][t][n][8]
  float* Ttb      = ws + off; off += 2ull*TSTR;         // [s][t][8][n] transposed
  float* Zb       = ws + off; off += 2ull*KT*N_E;       // 1/softmax-denominator
  float* ysumb    = ws + off; off += 2ull*KT*32;        // per-(s,t) colsum of y'
  float* x0b      = ws + off; off += 2ull*STRX;
  float* xAb      = ws + off; off += 2ull*STRX;
  unsigned short* ybf = (unsigned short*)(ws + off); off += (2ull*YSTR)/2;  // bf16 y'
  float* part     = ws + off;                           // rest of ws

  size_t slab = (size_t)N_E*32;                          // 65536 floats
  size_t avail_floats = (ws_size/4 > off) ? (ws_size/4 - off) : 0;
  int cap = (int)(avail_floats / slab);                  // total part slabs available

  float* epp = epb;              float* epa = epb + (size_t)KT*N_E*8;
  float* Ttp = Ttb;              float* Tta = Ttb + (size_t)TSTR;
  unsigned short* ybp = ybf;     unsigned short* yba = ybf + (size_t)YSTR;
  // stats partials alias onto `part`: consumed by k_zinv before first k_mixm writes it
  float* partC = part;           // needs 8 slabs (2 MB)

  k_embed<<<384,256,0,stream>>>(srv_attr, svc_attr, srv_tab0, srv_lvl, svc_tab0, svc_lvl, srv_emb, svc_emb);
  k_lstm <<<256,256,0,stream>>>(usr_tab, tra, Wih, Whh, bih, bhh, tra_feat);
  k_pe   <<<1408,256,0,stream>>>(edge, peWp, pebp, peWa, peba, epp, epa);
  k_T    <<<22,256,0,stream>>>(epp, epa, E1p, E2p, E1a, E2a, Ttp, Tta);
  k_stats<<<dim3(64,11,2),256,0,stream>>>(Ttp, Tta, epp, epa, partC);
  k_zinv <<<176,256,0,stream>>>(partC, Zb);
  k_proj <<<8192,256,0,stream>>>(loadx, svcx, prWp, prbp, prWa, prba, x0b, x0b + STRX);

  // per-layer active time sets (backward-propagated from t=15 output)
  const int Ldd[4]   = {1, 2, 1, 2};
  const int Ltb[4]   = {5, 9, 11, 15};
  const int Lts[4]   = {1, 1, 2, 1};
  const int Lnt[4]   = {11, 7, 3, 1};
  int Lsp[4]         = {4, 4, 8, 16};        // n-splits (occupancy vs part traffic)
  for (int i = 0; i < 4; i++)
    while (Lsp[i] > 1 && 2*Lnt[i]*Lsp[i] > cap) Lsp[i] >>= 1;

  float* xin = x0b;
  float* xout = xAb;
  for (int i = 0; i < 4; i++) {
    k_conv<<<dim3(256, Lnt[i], 2), 256, 0, stream>>>(
        xin, xin + STRX, Wtp, Wta, btp, bta, Zb, ybp, yba, i, Ldd[i], Ltb[i], Lts[i]);
    k_ysum<<<dim3(Lnt[i], 2), 256, 0, stream>>>(ybp, yba, ysumb, Ltb[i], Lts[i], Lnt[i]);
    k_mixm<<<dim3(32*Lsp[i], Lnt[i], 2), 256, 0, stream>>>(
        Ttp, Tta, epp, epa, ybp, yba, part, Ltb[i], Lts[i], Lnt[i], Lsp[i]);
    k_wg<<<dim3(256, Lnt[i], 2), 256, 0, stream>>>(
        part, ysumb, Wgp, Wga, bgp, bga, xout, xout + STRX, i, Ltb[i], Lts[i], Lnt[i], Lsp[i]);
    float* tmp = xin; xin = xout; xout = tmp;
  }
  // final stream features at t=15 live in xin
  const float* fpp = xin + (size_t)15*N_E*32;
  const float* fpa = xin + STRX + (size_t)15*N_E*32;

  k_mlp<<<128,64,0,stream>>>(info, tra_feat, fpp, fpa, srv_emb, svc_emb,
                             qW0, qb0, qW1, qb1, qW2, qb2, qW3, qb3, qW4, qb4, qW5, qb5, out);
}

// Round 9
// 488.517 us; speedup vs baseline: 1.3568x; 1.3133x over previous
//
#include <hip/hip_runtime.h>
#include <math.h>

#define N_E 2048
#define N_U 4096
#define N_SVC 1024
#define KT 16
#define STRX (KT*N_E*32)   // per-stream x buffer stride (floats)
#define YSTR (KT*N_E*32)   // per-stream y buffer stride (shorts)
#define TSTR (KT*8*N_E)    // per-stream T^T stride (floats)

typedef __attribute__((ext_vector_type(8))) short short8;   // 8 bf16 (4 VGPRs)
typedef __attribute__((ext_vector_type(4))) float f32x4;

__device__ __forceinline__ float sigf(float x){ return 1.0f/(1.0f+__expf(-x)); }
__device__ __forceinline__ float tanhfast(float x){ return 1.0f - 2.0f/(__expf(2.0f*x)+1.0f); }
__device__ __forceinline__ short f2bf(float f){
  union { float f; unsigned u; } x; x.f = f;
  unsigned r = x.u + 0x7FFFu + ((x.u >> 16) & 1u);
  return (short)(r >> 16);
}
__device__ __forceinline__ float bf2f(unsigned short u){
  union { unsigned u; float f; } x; x.u = ((unsigned)u) << 16; return x.f;
}
// expm1 via 4-term Taylor: rel err <1e-3 for d in [0,0.5]; d here is ~<0.05.
// Used identically in stats (denominator) and mixm (numerator) -> exact softmax row-sum.
__device__ __forceinline__ float expm1t(float d){
  float t = fmaf(d, 1.f/24.f, 1.f/6.f);
  t = fmaf(d, t, 0.5f);
  t = fmaf(d, t, 1.f);
  return d*t;
}

// ---------------- embeddings: srv_emb (2048x32), svc_emb (1024x32) ----------------
__global__ void k_embed(const int* __restrict__ srv_attr, const int* __restrict__ svc_attr,
                        const float* __restrict__ srv_tab0, const float* __restrict__ srv_lvl,
                        const float* __restrict__ svc_tab0, const float* __restrict__ svc_lvl,
                        float* __restrict__ srv_emb, float* __restrict__ svc_emb) {
  int idx = blockIdx.x*256 + threadIdx.x;       // (2048+1024) rows * 32 cols
  int r = idx >> 5, c = idx & 31;
  int seg = c >> 3, cc = c & 7;
  if (r < N_E) {
    int a = srv_attr[r*4 + seg];
    srv_emb[r*32 + c] = (seg==0) ? srv_tab0[a*8+cc] : srv_lvl[((seg-1)*10 + a)*8 + cc];
  } else {
    int r2 = r - N_E;
    if (r2 < N_SVC) {
      int a = svc_attr[r2*4 + seg];
      svc_emb[r2*32 + c] = (seg==0) ? svc_tab0[a*8+cc] : svc_lvl[((seg-1)*10 + a)*8 + cc];
    }
  }
}

// ---------------- LSTM: 16 lanes per user, lane j owns hidden unit j ----------------
__global__ __launch_bounds__(256) void k_lstm(const float* __restrict__ usr_tab, const float* __restrict__ tra,
                       const float* __restrict__ Wih, const float* __restrict__ Whh,
                       const float* __restrict__ bih, const float* __restrict__ bhh,
                       float* __restrict__ tra_feat) {
  __shared__ float sWih[64*12];
  __shared__ float sWhh[64*16];
  __shared__ float sB[64];
  int tid = threadIdx.x;
  for (int i = tid; i < 64*12; i += 256) sWih[i] = Wih[i];
  for (int i = tid; i < 64*16; i += 256) sWhh[i] = Whh[i];
  if (tid < 64) sB[tid] = bih[tid] + bhh[tid];
  __syncthreads();
  int j  = tid & 15;
  int u  = blockIdx.x*16 + (tid >> 4);
  float xe[8];
  #pragma unroll
  for (int k=0;k<8;k++) xe[k] = usr_tab[u*8+k];
  float h = 0.f, c = 0.f;
  for (int t=0;t<KT;t++) {
    float gi = sB[j], gf = sB[16+j], gg = sB[32+j], go = sB[48+j];
    #pragma unroll
    for (int k=0;k<8;k++) {
      float v = xe[k];
      gi += sWih[j*12+k]*v;      gf += sWih[(16+j)*12+k]*v;
      gg += sWih[(32+j)*12+k]*v; go += sWih[(48+j)*12+k]*v;
    }
    #pragma unroll
    for (int k=0;k<4;k++) {
      float v = tra[((size_t)t*N_U + u)*4 + k];
      gi += sWih[j*12+8+k]*v;      gf += sWih[(16+j)*12+8+k]*v;
      gg += sWih[(32+j)*12+8+k]*v; go += sWih[(48+j)*12+8+k]*v;
    }
    #pragma unroll
    for (int jj=0;jj<16;jj++) {
      float hv = __shfl(h, jj, 16);
      gi += sWhh[j*16+jj]*hv;      gf += sWhh[(16+j)*16+jj]*hv;
      gg += sWhh[(32+j)*16+jj]*hv; go += sWhh[(48+j)*16+jj]*hv;
    }
    c = sigf(gf)*c + sigf(gi)*tanhfast(gg);
    h = sigf(go)*tanhfast(c);
  }
  tra_feat[u*16 + j] = h;
}

// ------- fused pe + T: ep = edge@W^T+b; Tt[v][n] = (ep@(E2.E1))^T; only t in [5,15] -------
__global__ __launch_bounds__(256) void k_peT(const float* __restrict__ edge,
                    const float* __restrict__ Wp, const float* __restrict__ bp,
                    const float* __restrict__ Wa, const float* __restrict__ ba,
                    const float* __restrict__ E1p, const float* __restrict__ E2p,
                    const float* __restrict__ E1a, const float* __restrict__ E2a,
                    float* __restrict__ epp, float* __restrict__ epa,
                    float* __restrict__ Ttp, float* __restrict__ Tta) {
  __shared__ float sM[64];
  __shared__ float sW[88];
  __shared__ float sb[8];
  int s = blockIdx.z, t = 5 + blockIdx.y;
  const float* E1 = s ? E1a : E1p;
  const float* E2 = s ? E2a : E2p;
  const float* W  = s ? Wa : Wp;
  const float* b  = s ? ba : bp;
  float* ep = (s ? epa : epp) + (size_t)t*N_E*8;
  float* Tt = (s ? Tta : Ttp) + (size_t)t*8*N_E;
  int tid = threadIdx.x;
  if (tid < 64) {
    int u = tid >> 3, v = tid & 7;
    float m = 0.f;
    #pragma unroll
    for (int o=0;o<8;o++) m += E2[t*8+o]*E1[(o*8+u)*8+v];
    sM[u*8+v] = m;
  }
  if (tid >= 64 && tid < 152) sW[tid-64] = W[tid-64];
  if (tid >= 152 && tid < 160) sb[tid-152] = b[tid-152];
  __syncthreads();
  int n = blockIdx.x*256 + tid;
  const float* e = edge + ((size_t)t*N_E + n)*11;
  float ev[11];
  #pragma unroll
  for (int k=0;k<11;k++) ev[k] = e[k];
  float epr[8];
  #pragma unroll
  for (int c=0;c<8;c++) {
    float acc = sb[c];
    #pragma unroll
    for (int k=0;k<11;k++) acc = fmaf(ev[k], sW[c*11+k], acc);
    epr[c] = acc;
  }
  float4* eo = (float4*)(ep + (size_t)n*8);
  eo[0] = make_float4(epr[0],epr[1],epr[2],epr[3]);
  eo[1] = make_float4(epr[4],epr[5],epr[6],epr[7]);
  #pragma unroll
  for (int v=0;v<8;v++) {
    float acc = 0.f;
    #pragma unroll
    for (int u=0;u<8;u++) acc = fmaf(epr[u], sM[u*8+v], acc);
    Tt[(size_t)v*N_E + n] = acc;   // coalesced across lanes
  }
}

// --------- softmax row partials: partC = 256 + sum_m expm1t(relu(T[n].ep[m])) (pure FMA) ---------
__global__ __launch_bounds__(256) void k_stats(const float* __restrict__ Ttp, const float* __restrict__ Tta,
                        const float* __restrict__ epp, const float* __restrict__ epa,
                        float* __restrict__ partC) {
  __shared__ float sE[256*8];   // 8 KiB
  int s = blockIdx.z, t = 5 + blockIdx.y;
  int ntile = blockIdx.x & 7, sp = blockIdx.x >> 3;
  int n = ntile*256 + threadIdx.x;
  const float* Tt = (s ? Tta : Ttp) + (size_t)t*8*N_E;
  const float* E = (s ? epa : epp) + (size_t)t*N_E*8;
  int tid = threadIdx.x;
  float tr[8];
  #pragma unroll
  for (int v=0;v<8;v++) tr[v] = Tt[(size_t)v*N_E + n];   // coalesced
  int m0 = sp*256;
  {
    const float4* ge = (const float4*)(E + (size_t)m0*8);
    float4* se = (float4*)sE;
    for (int i = tid; i < 512; i += 256) se[i] = ge[i];
  }
  __syncthreads();
  float qs = 0.f;
  #pragma unroll 4
  for (int m = 0; m < 256; m++) {
    float d = 0.f;
    #pragma unroll
    for (int v=0;v<8;v++) d = fmaf(sE[m*8+v], tr[v], d);
    qs += expm1t(fmaxf(d, 0.f));
  }
  partC[(((size_t)s*KT + t)*8 + sp)*N_E + n] = 256.f + qs;
}

// ---------------- Zinv = 1 / (sum of 8 partials), t in [5,15] ----------------
__global__ void k_zinv(const float* __restrict__ partC, float* __restrict__ Z) {
  int i = blockIdx.x*256 + threadIdx.x;   // 2*11*2048 = 45056
  int n = i & 2047; int stp = i >> 11;    // [0,22)
  int s = stp / 11, t = 5 + stp % 11;
  float a = 0.f;
  #pragma unroll
  for (int sp=0;sp<8;sp++) a += partC[(((size_t)s*KT + t)*8 + sp)*N_E + n];
  Z[((size_t)s*KT + t)*N_E + n] = 1.0f/a;
}

// ---------------- x0 = proj(load / svc_tot) : (16,2048,32) x2 ----------------
__global__ void k_proj(const float* __restrict__ loadx, const float* __restrict__ svcx,
                       const float* __restrict__ Wp, const float* __restrict__ bp,
                       const float* __restrict__ Wa, const float* __restrict__ ba,
                       float* __restrict__ x0p, float* __restrict__ x0a) {
  int idx = blockIdx.x*256 + threadIdx.x;        // s t n g : 21 bits
  int g = idx & 31; int rest = idx >> 5;
  int n = rest & 2047; rest >>= 11; int t = rest & 15; int s = rest >> 4;
  const float* in = (s ? svcx : loadx) + ((size_t)t*N_E + n)*3;
  const float* W = s ? Wa : Wp; const float* b = s ? ba : bp;
  float acc = b[g];
  #pragma unroll
  for (int c=0;c<3;c++) acc += in[c]*W[g*3+c];
  (s ? x0a : x0p)[((size_t)t*N_E + n)*32 + g] = acc;
}

// --- dilated causal conv + ReLU, scaled by Zinv[n], output bf16; fused colsum via atomics ---
__global__ __launch_bounds__(256) void k_conv(const float* __restrict__ xp, const float* __restrict__ xa,
                       const float* __restrict__ Wtp, const float* __restrict__ Wta,
                       const float* __restrict__ btp, const float* __restrict__ bta,
                       const float* __restrict__ Zg,
                       unsigned short* __restrict__ yp, unsigned short* __restrict__ ya,
                       float* __restrict__ ysumb,
                       int layer, int dd, int tbase, int tstep) {
  __shared__ float sW[3*32*32];
  __shared__ float sX[8][3][32];
  __shared__ float rsum[256];
  int s = blockIdx.z;
  int t = tbase + blockIdx.y*tstep;
  const float* x  = s ? xa : xp;
  const float* Wt = (s ? Wta : Wtp) + (size_t)layer*3*32*32;
  const float* bt = (s ? bta : btp) + layer*32;
  unsigned short* y = s ? ya : yp;
  int tid = threadIdx.x;
  for (int i = tid; i < 3*32*32; i += 256) sW[i] = Wt[i];
  int n0 = blockIdx.x*8;
  for (int i = tid; i < 768; i += 256) {
    int f = i & 31; int nn = (i>>5)&7; int j = i >> 8;
    int tt = t - (2-j)*dd;
    sX[nn][j][f] = (tt >= 0) ? x[((size_t)tt*N_E + n0+nn)*32 + f] : 0.f;
  }
  __syncthreads();
  int g = tid & 31, nn = tid >> 5;
  float acc = bt[g];
  #pragma unroll
  for (int j=0;j<3;j++)
    #pragma unroll
    for (int f=0;f<32;f++) acc += sX[nn][j][f]*sW[(j*32+f)*32+g];
  float zi = Zg[((size_t)s*KT + t)*N_E + n0+nn];
  float val = fmaxf(acc, 0.f)*zi;
  y[((size_t)t*N_E + n0+nn)*32 + g] = (unsigned short)f2bf(val);
  rsum[tid] = val;
  __syncthreads();
  if (tid < 32) {
    float a = 0.f;
    #pragma unroll
    for (int k=0;k<8;k++) a += rsum[tid + 32*k];
    atomicAdd(&ysumb[((size_t)s*gridDim.y + blockIdx.y)*32 + tid], a);
  }
}

// --------- MFMA mixing, double-buffered LDS (1 barrier/chunk, loads 1 chunk ahead) ---------
// part[m,f] = sum_n q[n,m]*y'[n,f], q = expm1t(relu(T[n].ep[m])); out = colsum(y') + q-term
__global__ __launch_bounds__(256) void k_mixm(const float* __restrict__ Ttp, const float* __restrict__ Tta,
                      const float* __restrict__ epp, const float* __restrict__ epa,
                      const unsigned short* __restrict__ ybp, const unsigned short* __restrict__ yba,
                      float* __restrict__ part,
                      int tbase, int tstep, int nt, int nsplit) {
  __shared__ float sTt[2][8*132];             // 2 x 4.2 KiB
  __shared__ unsigned short sYb[2][128*34];   // 2 x 8.5 KiB
  int s = blockIdx.z, ty = blockIdx.y;
  int t = tbase + ty*tstep;
  int mtile = blockIdx.x & 31, split = blockIdx.x >> 5;
  int tid = threadIdx.x;
  int w = tid >> 6, lane = tid & 63;
  int g = lane >> 4, fc = lane & 15;
  int m0 = mtile*64 + w*16;
  const float* Tt = (s ? Tta : Ttp) + (size_t)t*8*N_E;
  const float* ep = (s ? epa : epp) + (size_t)t*N_E*8;
  const unsigned short* yb = (s ? yba : ybp) + (size_t)t*N_E*32;
  float er[8];
  {
    const float4* gep = (const float4*)(ep + (size_t)(m0 + fc)*8);
    float4 a = gep[0], b = gep[1];
    er[0]=a.x; er[1]=a.y; er[2]=a.z; er[3]=a.w;
    er[4]=b.x; er[5]=b.y; er[6]=b.z; er[7]=b.w;
  }
  f32x4 acc0 = {0.f,0.f,0.f,0.f}, acc1 = {0.f,0.f,0.f,0.f};
  int n0 = split*(N_E/nsplit);
  int nc = (N_E/nsplit)/128;                 // chunks
  int tv = tid >> 5, tc = tid & 31;          // T-stage coords
  float4 tReg, yR0, yR1;
  {
    tReg = *(const float4*)(Tt + (size_t)tv*N_E + n0 + tc*4);
    const float4* gy = (const float4*)(yb + (size_t)n0*32);
    yR0 = gy[tid]; yR1 = gy[tid + 256];
  }
  for (int ci = 0; ci < nc; ci++) {
    int buf = ci & 1;
    // write staged regs to LDS[buf]  (safe: all waves finished computing buf 2 iters ago
    // before passing the previous barrier — compute(c) precedes write(c+1) in program order)
    *(float4*)&sTt[buf][tv*132 + tc*4] = tReg;
    {
      union { float4 f; unsigned u[4]; } cv;
      cv.f = yR0;
      unsigned* d0 = (unsigned*)&sYb[buf][(tid>>2)*34 + (tid&3)*8];
      d0[0]=cv.u[0]; d0[1]=cv.u[1]; d0[2]=cv.u[2]; d0[3]=cv.u[3];
      cv.f = yR1;
      unsigned* d1 = (unsigned*)&sYb[buf][(64 + (tid>>2))*34 + (tid&3)*8];
      d1[0]=cv.u[0]; d1[1]=cv.u[1]; d1[2]=cv.u[2]; d1[3]=cv.u[3];
    }
    if (ci + 1 < nc) {   // issue next chunk's loads; a full compute phase hides them
      int c1 = n0 + (ci+1)*128;
      tReg = *(const float4*)(Tt + (size_t)tv*N_E + c1 + tc*4);
      const float4* gy = (const float4*)(yb + (size_t)c1*32);
      yR0 = gy[tid]; yR1 = gy[tid + 256];
    }
    __syncthreads();
    #pragma unroll
    for (int sub = 0; sub < 4; sub++) {
      int rbase = sub*32 + g*8;
      f32x4 dA = {0.f,0.f,0.f,0.f}, dB = {0.f,0.f,0.f,0.f};
      #pragma unroll
      for (int v=0; v<8; v++) {
        const f32x4* tvp = (const f32x4*)&sTt[buf][v*132 + rbase];  // 16B-aligned
        f32x4 ta = tvp[0], tb = tvp[1];
        float e = er[v];
        dA += ta * e;
        dB += tb * e;
      }
      short8 af;
      #pragma unroll
      for (int i=0;i<4;i++) af[i]   = f2bf(expm1t(fmaxf(dA[i], 0.f)));
      #pragma unroll
      for (int i=0;i<4;i++) af[4+i] = f2bf(expm1t(fmaxf(dB[i], 0.f)));
      short8 bf0, bf1;
      #pragma unroll
      for (int i=0;i<8;i++) {
        int row = (rbase + i)*34;
        bf0[i] = (short)sYb[buf][row + fc];
        bf1[i] = (short)sYb[buf][row + 16 + fc];
      }
      acc0 = __builtin_amdgcn_mfma_f32_16x16x32_bf16(af, bf0, acc0, 0, 0, 0);
      acc1 = __builtin_amdgcn_mfma_f32_16x16x32_bf16(af, bf1, acc1, 0, 0, 0);
    }
  }
  float* pb = part + (size_t)((s*nt + ty)*nsplit + split)*(N_E*32);
  #pragma unroll
  for (int r=0;r<4;r++) {
    pb[(size_t)(m0 + g*4 + r)*32 + fc]      = acc0[r];
    pb[(size_t)(m0 + g*4 + r)*32 + 16 + fc] = acc1[r];
  }
}

// ---------------- reduce nsplit partials + ysum + Wg + bias + ReLU ----------------
__global__ __launch_bounds__(256) void k_wg(const float* __restrict__ part,
                     const float* __restrict__ ysumb,
                     const float* __restrict__ Wgp, const float* __restrict__ Wga,
                     const float* __restrict__ bgp, const float* __restrict__ bga,
                     float* __restrict__ xop, float* __restrict__ xoa,
                     int layer, int tbase, int tstep, int nt, int nsplit) {
  __shared__ float sX[8*32];
  __shared__ float sWg[32*32];
  __shared__ float sBg[32];
  int s = blockIdx.z, ty = blockIdx.y;
  int t = tbase + ty*tstep;
  int m0 = blockIdx.x*8;
  const float* Wg = (s ? Wga : Wgp) + (size_t)layer*1024;
  const float* bg = (s ? bga : bgp) + layer*32;
  int tid = threadIdx.x;
  for (int i = tid; i < 1024; i += 256) sWg[i] = Wg[i];
  if (tid < 32) sBg[tid] = bg[tid];
  {
    int mm = tid >> 5, f = tid & 31;
    const float* p = part + (size_t)((s*nt + ty)*nsplit)*(N_E*32) + (size_t)(m0+mm)*32 + f;
    float a = ysumb[((size_t)s*nt + ty)*32 + f];
    for (int sp = 0; sp < nsplit; sp++) a += p[(size_t)sp*(N_E*32)];
    sX[mm*32+f] = a;
  }
  __syncthreads();
  int mm = tid >> 5, g = tid & 31;
  float a = sBg[g];
  #pragma unroll
  for (int f=0;f<32;f++) a += sX[mm*32+f]*sWg[f*32+g];
  (s ? xoa : xop)[((size_t)t*N_E + m0+mm)*32 + g] = fmaxf(a, 0.f);
}

// ---------------- fused gather + 6-layer MLP head, LDS-resident transposed weights ----------------
__global__ __launch_bounds__(64) void k_mlp(const int* __restrict__ info,
    const float* __restrict__ tf, const float* __restrict__ fpp, const float* __restrict__ fpa,
    const float* __restrict__ se, const float* __restrict__ ve,
    const float* __restrict__ W0, const float* __restrict__ b0,
    const float* __restrict__ W1, const float* __restrict__ b1,
    const float* __restrict__ W2, const float* __restrict__ b2,
    const float* __restrict__ W3, const float* __restrict__ b3,
    const float* __restrict__ W4, const float* __restrict__ b4,
    const float* __restrict__ W5, const float* __restrict__ b5,
    float* __restrict__ out) {
  __shared__ float sW0t[112*64];   // [k][g] transposed, 28 KiB
  __shared__ float sW1t[64*32];
  __shared__ float sW2t[32*16];
  __shared__ float sW3t[16*8];
  __shared__ float sW4t[8*4];
  __shared__ float sW5[4];
  __shared__ float sB0[64];
  __shared__ float sB1[32];
  __shared__ float sB2[16];
  __shared__ float sB3[8];
  __shared__ float sB4[4];
  __shared__ float sB5[1];
  int tid = threadIdx.x;
  for (int i = tid; i < 1792; i += 64) {        // W0: 64x112 floats, f4 along k
    float4 v = ((const float4*)W0)[i];
    int g = i / 28, kq = (i % 28)*4;
    sW0t[(kq+0)*64+g]=v.x; sW0t[(kq+1)*64+g]=v.y; sW0t[(kq+2)*64+g]=v.z; sW0t[(kq+3)*64+g]=v.w;
  }
  for (int i = tid; i < 2048; i += 64) sW1t[(i&63)*32 + (i>>6)] = W1[i];   // W1: 32x64
  for (int i = tid; i < 512; i += 64)  sW2t[(i&31)*16 + (i>>5)] = W2[i];   // W2: 16x32
  for (int i = tid; i < 128; i += 64)  sW3t[(i&15)*8  + (i>>4)] = W3[i];   // W3: 8x16
  if (tid < 32) sW4t[(tid&7)*4 + (tid>>3)] = W4[tid];                      // W4: 4x8
  if (tid < 4)  sW5[tid] = W5[tid];
  if (tid < 64) sB0[tid] = b0[tid];
  if (tid < 32) sB1[tid] = b1[tid];
  if (tid < 16) sB2[tid] = b2[tid];
  if (tid < 8)  sB3[tid] = b3[tid];
  if (tid < 4)  sB4[tid] = b4[tid];
  if (tid == 0) sB5[0] = b5[0];
  __syncthreads();

  int r = blockIdx.x*64 + tid;
  int4 ifo = ((const int4*)info)[r];
  int uid = ifo.x, eid = ifo.y, sid = ifo.z;

  f32x4 o0v[16];
  #pragma unroll
  for (int gq=0;gq<16;gq++) {
    o0v[gq][0]=sB0[gq*4]; o0v[gq][1]=sB0[gq*4+1]; o0v[gq][2]=sB0[gq*4+2]; o0v[gq][3]=sB0[gq*4+3];
  }
  {
    const float4* p = (const float4*)(tf + (size_t)uid*16);
    #pragma unroll
    for (int q=0;q<4;q++) {
      float4 v4 = p[q];
      #pragma unroll
      for (int j=0;j<4;j++) {
        float v = (&v4.x)[j];
        const f32x4* wc = (const f32x4*)&sW0t[(q*4+j)*64];
        #pragma unroll
        for (int gq=0;gq<16;gq++) o0v[gq] += wc[gq]*v;
      }
    }
  }
  {
    const float4* pp = (const float4*)(fpp + (size_t)eid*32);
    const float4* pa = (const float4*)(fpa + (size_t)eid*32);
    #pragma unroll
    for (int q=0;q<8;q++) {
      float4 a4 = pp[q], b4 = pa[q];
      #pragma unroll
      for (int j=0;j<4;j++) {
        float v = 0.5f*((&a4.x)[j] + (&b4.x)[j]);
        const f32x4* wc = (const f32x4*)&sW0t[(16+q*4+j)*64];
        #pragma unroll
        for (int gq=0;gq<16;gq++) o0v[gq] += wc[gq]*v;
      }
    }
  }
  {
    const float4* p = (const float4*)(se + (size_t)eid*32);
    #pragma unroll
    for (int q=0;q<8;q++) {
      float4 v4 = p[q];
      #pragma unroll
      for (int j=0;j<4;j++) {
        float v = (&v4.x)[j];
        const f32x4* wc = (const f32x4*)&sW0t[(48+q*4+j)*64];
        #pragma unroll
        for (int gq=0;gq<16;gq++) o0v[gq] += wc[gq]*v;
      }
    }
  }
  {
    const float4* p = (const float4*)(ve + (size_t)sid*32);
    #pragma unroll
    for (int q=0;q<8;q++) {
      float4 v4 = p[q];
      #pragma unroll
      for (int j=0;j<4;j++) {
        float v = (&v4.x)[j];
        const f32x4* wc = (const f32x4*)&sW0t[(80+q*4+j)*64];
        #pragma unroll
        for (int gq=0;gq<16;gq++) o0v[gq] += wc[gq]*v;
      }
    }
  }
  #pragma unroll
  for (int gq=0;gq<16;gq++) {
    #pragma unroll
    for (int j=0;j<4;j++) o0v[gq][j] = fmaxf(o0v[gq][j], 0.f);
  }
  f32x4 o1v[8];
  #pragma unroll
  for (int gq=0;gq<8;gq++) {
    o1v[gq][0]=sB1[gq*4]; o1v[gq][1]=sB1[gq*4+1]; o1v[gq][2]=sB1[gq*4+2]; o1v[gq][3]=sB1[gq*4+3];
  }
  #pragma unroll
  for (int k=0;k<64;k++) {
    float v = o0v[k>>2][k&3];
    const f32x4* wc = (const f32x4*)&sW1t[k*32];
    #pragma unroll
    for (int gq=0;gq<8;gq++) o1v[gq] += wc[gq]*v;
  }
  #pragma unroll
  for (int gq=0;gq<8;gq++) {
    #pragma unroll
    for (int j=0;j<4;j++) o1v[gq][j] = fmaxf(o1v[gq][j], 0.f);
  }
  float o2[16];
  #pragma unroll
  for (int g=0;g<16;g++) o2[g] = sB2[g];
  #pragma unroll
  for (int k=0;k<32;k++) {
    float v = o1v[k>>2][k&3];
    #pragma unroll
    for (int g=0;g<16;g++) o2[g] = fmaf(sW2t[k*16+g], v, o2[g]);
  }
  #pragma unroll
  for (int g=0;g<16;g++) o2[g] = fmaxf(o2[g], 0.f);
  float o3[8];
  #pragma unroll
  for (int g=0;g<8;g++) o3[g] = sB3[g];
  #pragma unroll
  for (int k=0;k<16;k++) {
    float v = o2[k];
    #pragma unroll
    for (int g=0;g<8;g++) o3[g] = fmaf(sW3t[k*8+g], v, o3[g]);
  }
  #pragma unroll
  for (int g=0;g<8;g++) o3[g] = fmaxf(o3[g], 0.f);
  float o4[4];
  #pragma unroll
  for (int g=0;g<4;g++) o4[g] = sB4[g];
  #pragma unroll
  for (int k=0;k<8;k++) {
    float v = o3[k];
    #pragma unroll
    for (int g=0;g<4;g++) o4[g] = fmaf(sW4t[k*4+g], v, o4[g]);
  }
  #pragma unroll
  for (int g=0;g<4;g++) o4[g] = fmaxf(o4[g], 0.f);
  float o5 = sB5[0];
  #pragma unroll
  for (int k=0;k<4;k++) o5 = fmaf(sW5[k], o4[k], o5);
  out[r] = o5;
}

extern "C" void kernel_launch(void* const* d_in, const int* in_sizes, int n_in,
                              void* d_out, int out_size, void* d_ws, size_t ws_size,
                              hipStream_t stream) {
  (void)in_sizes; (void)n_in; (void)out_size;
  const float* edge    = (const float*)d_in[0];
  const float* loadx   = (const float*)d_in[1];
  const float* svcx    = (const float*)d_in[2];
  const float* tra     = (const float*)d_in[3];
  const int*   info    = (const int*)d_in[4];
  const int*   srv_attr= (const int*)d_in[5];
  const int*   svc_attr= (const int*)d_in[6];
  const float* usr_tab = (const float*)d_in[7];
  const float* srv_tab0= (const float*)d_in[8];
  const float* srv_lvl = (const float*)d_in[9];
  const float* svc_tab0= (const float*)d_in[10];
  const float* svc_lvl = (const float*)d_in[11];
  const float* Wih = (const float*)d_in[12];
  const float* Whh = (const float*)d_in[13];
  const float* bih = (const float*)d_in[14];
  const float* bhh = (const float*)d_in[15];
  const float* E1p = (const float*)d_in[16];
  const float* E2p = (const float*)d_in[17];
  const float* peWp= (const float*)d_in[18];
  const float* pebp= (const float*)d_in[19];
  const float* E1a = (const float*)d_in[20];
  const float* E2a = (const float*)d_in[21];
  const float* peWa= (const float*)d_in[22];
  const float* peba= (const float*)d_in[23];
  const float* prWp= (const float*)d_in[24];
  const float* prbp= (const float*)d_in[25];
  const float* prWa= (const float*)d_in[26];
  const float* prba= (const float*)d_in[27];
  const float* Wtp = (const float*)d_in[28];
  const float* btp = (const float*)d_in[29];
  const float* Wgp = (const float*)d_in[30];
  const float* bgp = (const float*)d_in[31];
  const float* Wta = (const float*)d_in[32];
  const float* bta = (const float*)d_in[33];
  const float* Wga = (const float*)d_in[34];
  const float* bga = (const float*)d_in[35];
  const float* qW0 = (const float*)d_in[36]; const float* qb0 = (const float*)d_in[37];
  const float* qW1 = (const float*)d_in[38]; const float* qb1 = (const float*)d_in[39];
  const float* qW2 = (const float*)d_in[40]; const float* qb2 = (const float*)d_in[41];
  const float* qW3 = (const float*)d_in[42]; const float* qb3 = (const float*)d_in[43];
  const float* qW4 = (const float*)d_in[44]; const float* qb4 = (const float*)d_in[45];
  const float* qW5 = (const float*)d_in[46]; const float* qb5 = (const float*)d_in[47];
  float* out = (float*)d_out;

  // workspace layout (floats); part sized from remaining ws
  float* ws = (float*)d_ws;
  size_t off = 0;
  float* srv_emb  = ws + off; off += (size_t)N_E*32;
  float* svc_emb  = ws + off; off += (size_t)N_SVC*32;
  float* tra_feat = ws + off; off += (size_t)N_U*16;
  float* epb      = ws + off; off += 2ull*KT*N_E*8;     // [s][t][n][8]
  float* Ttb      = ws + off; off += 2ull*TSTR;         // [s][t][8][n] transposed
  float* Zb       = ws + off; off += 2ull*KT*N_E;       // 1/softmax-denominator
  float* ysumb    = ws + off; off += 2ull*KT*32;        // per-(s,t) colsum of y' (atomics)
  float* x0b      = ws + off; off += 2ull*STRX;
  float* xAb      = ws + off; off += 2ull*STRX;
  unsigned short* ybf = (unsigned short*)(ws + off); off += (2ull*YSTR)/2;  // bf16 y'
  float* part     = ws + off;                           // rest of ws

  size_t slab = (size_t)N_E*32;                          // 65536 floats
  size_t avail_floats = (ws_size/4 > off) ? (ws_size/4 - off) : 0;
  int cap = (int)(avail_floats / slab);                  // total part slabs available

  float* epp = epb;              float* epa = epb + (size_t)KT*N_E*8;
  float* Ttp = Ttb;              float* Tta = Ttb + (size_t)TSTR;
  unsigned short* ybp = ybf;     unsigned short* yba = ybf + (size_t)YSTR;
  // stats partials alias onto `part`: consumed by k_zinv before first k_mixm writes it
  float* partC = part;           // needs 8 slabs (2 MB)

  k_embed<<<384,256,0,stream>>>(srv_attr, svc_attr, srv_tab0, srv_lvl, svc_tab0, svc_lvl, srv_emb, svc_emb);
  k_lstm <<<256,256,0,stream>>>(usr_tab, tra, Wih, Whh, bih, bhh, tra_feat);
  k_peT  <<<dim3(8,11,2),256,0,stream>>>(edge, peWp, pebp, peWa, peba,
                                         E1p, E2p, E1a, E2a, epp, epa, Ttp, Tta);
  k_stats<<<dim3(64,11,2),256,0,stream>>>(Ttp, Tta, epp, epa, partC);
  k_zinv <<<176,256,0,stream>>>(partC, Zb);
  k_proj <<<8192,256,0,stream>>>(loadx, svcx, prWp, prbp, prWa, prba, x0b, x0b + STRX);

  // per-layer active time sets (backward-propagated from t=15 output)
  const int Ldd[4]   = {1, 2, 1, 2};
  const int Ltb[4]   = {5, 9, 11, 15};
  const int Lts[4]   = {1, 1, 2, 1};
  const int Lnt[4]   = {11, 7, 3, 1};
  int Lsp[4]         = {4, 4, 8, 16};        // n-splits (occupancy vs part traffic)
  for (int i = 0; i < 4; i++)
    while (Lsp[i] > 1 && 2*Lnt[i]*Lsp[i] > cap) Lsp[i] >>= 1;

  float* xin = x0b;
  float* xout = xAb;
  for (int i = 0; i < 4; i++) {
    hipMemsetAsync(ysumb, 0, 2ull*KT*32*sizeof(float), stream);   // zero atomic colsum buffer
    k_conv<<<dim3(256, Lnt[i], 2), 256, 0, stream>>>(
        xin, xin + STRX, Wtp, Wta, btp, bta, Zb, ybp, yba, ysumb, i, Ldd[i], Ltb[i], Lts[i]);
    k_mixm<<<dim3(32*Lsp[i], Lnt[i], 2), 256, 0, stream>>>(
        Ttp, Tta, epp, epa, ybp, yba, part, Ltb[i], Lts[i], Lnt[i], Lsp[i]);
    k_wg<<<dim3(256, Lnt[i], 2), 256, 0, stream>>>(
        part, ysumb, Wgp, Wga, bgp, bga, xout, xout + STRX, i, Ltb[i], Lts[i], Lnt[i], Lsp[i]);
    float* tmp = xin; xin = xout; xout = tmp;
  }
  // final stream features at t=15 live in xin
  const float* fpp = xin + (size_t)15*N_E*32;
  const float* fpa = xin + STRX + (size_t)15*N_E*32;

  k_mlp<<<128,64,0,stream>>>(info, tra_feat, fpp, fpa, srv_emb, svc_emb,
                             qW0, qb0, qW1, qb1, qW2, qb2, qW3, qb3, qW4, qb4, qW5, qb5, out);
}

// Round 10
// 471.848 us; speedup vs baseline: 1.4048x; 1.0353x over previous
//
#include <hip/hip_runtime.h>
#include <math.h>

#define N_E 2048
#define N_U 4096
#define N_SVC 1024
#define KT 16
#define STRX (KT*N_E*32)   // per-stream x buffer stride (floats)
#define YSTR (KT*N_E*32)   // per-stream y buffer stride (shorts)
#define TSTR (KT*8*N_E)    // per-stream T^T stride (floats)

typedef __attribute__((ext_vector_type(8))) short short8;   // 8 bf16 (4 VGPRs)
typedef __attribute__((ext_vector_type(4))) float f32x4;

__device__ __forceinline__ float sigf(float x){ return 1.0f/(1.0f+__expf(-x)); }
__device__ __forceinline__ float tanhfast(float x){ return 1.0f - 2.0f/(__expf(2.0f*x)+1.0f); }
__device__ __forceinline__ short f2bf(float f){
  union { float f; unsigned u; } x; x.f = f;
  unsigned r = x.u + 0x7FFFu + ((x.u >> 16) & 1u);
  return (short)(r >> 16);
}
__device__ __forceinline__ float bf2f(unsigned short u){
  union { unsigned u; float f; } x; x.u = ((unsigned)u) << 16; return x.f;
}
// expm1 via 4-term Taylor; d here is ~<0.05. Used identically in stats (denominator)
// and mixm (numerator) -> softmax rows sum to exactly 1.
__device__ __forceinline__ float expm1t(float d){
  float t = fmaf(d, 1.f/24.f, 1.f/6.f);
  t = fmaf(d, t, 0.5f);
  t = fmaf(d, t, 1.f);
  return d*t;
}

// ---------------- embeddings: srv_emb (2048x32), svc_emb (1024x32) ----------------
__global__ void k_embed(const int* __restrict__ srv_attr, const int* __restrict__ svc_attr,
                        const float* __restrict__ srv_tab0, const float* __restrict__ srv_lvl,
                        const float* __restrict__ svc_tab0, const float* __restrict__ svc_lvl,
                        float* __restrict__ srv_emb, float* __restrict__ svc_emb) {
  int idx = blockIdx.x*256 + threadIdx.x;       // (2048+1024) rows * 32 cols
  int r = idx >> 5, c = idx & 31;
  int seg = c >> 3, cc = c & 7;
  if (r < N_E) {
    int a = srv_attr[r*4 + seg];
    srv_emb[r*32 + c] = (seg==0) ? srv_tab0[a*8+cc] : srv_lvl[((seg-1)*10 + a)*8 + cc];
  } else {
    int r2 = r - N_E;
    if (r2 < N_SVC) {
      int a = svc_attr[r2*4 + seg];
      svc_emb[r2*32 + c] = (seg==0) ? svc_tab0[a*8+cc] : svc_lvl[((seg-1)*10 + a)*8 + cc];
    }
  }
}

// ---------------- LSTM: 16 lanes per user, lane j owns hidden unit j ----------------
__global__ __launch_bounds__(256) void k_lstm(const float* __restrict__ usr_tab, const float* __restrict__ tra,
                       const float* __restrict__ Wih, const float* __restrict__ Whh,
                       const float* __restrict__ bih, const float* __restrict__ bhh,
                       float* __restrict__ tra_feat) {
  __shared__ float sWih[64*12];
  __shared__ float sWhh[64*16];
  __shared__ float sB[64];
  int tid = threadIdx.x;
  for (int i = tid; i < 64*12; i += 256) sWih[i] = Wih[i];
  for (int i = tid; i < 64*16; i += 256) sWhh[i] = Whh[i];
  if (tid < 64) sB[tid] = bih[tid] + bhh[tid];
  __syncthreads();
  int j  = tid & 15;
  int u  = blockIdx.x*16 + (tid >> 4);
  float xe[8];
  #pragma unroll
  for (int k=0;k<8;k++) xe[k] = usr_tab[u*8+k];
  float h = 0.f, c = 0.f;
  for (int t=0;t<KT;t++) {
    float gi = sB[j], gf = sB[16+j], gg = sB[32+j], go = sB[48+j];
    #pragma unroll
    for (int k=0;k<8;k++) {
      float v = xe[k];
      gi += sWih[j*12+k]*v;      gf += sWih[(16+j)*12+k]*v;
      gg += sWih[(32+j)*12+k]*v; go += sWih[(48+j)*12+k]*v;
    }
    #pragma unroll
    for (int k=0;k<4;k++) {
      float v = tra[((size_t)t*N_U + u)*4 + k];
      gi += sWih[j*12+8+k]*v;      gf += sWih[(16+j)*12+8+k]*v;
      gg += sWih[(32+j)*12+8+k]*v; go += sWih[(48+j)*12+8+k]*v;
    }
    #pragma unroll
    for (int jj=0;jj<16;jj++) {
      float hv = __shfl(h, jj, 16);
      gi += sWhh[j*16+jj]*hv;      gf += sWhh[(16+j)*16+jj]*hv;
      gg += sWhh[(32+j)*16+jj]*hv; go += sWhh[(48+j)*16+jj]*hv;
    }
    c = sigf(gf)*c + sigf(gi)*tanhfast(gg);
    h = sigf(go)*tanhfast(c);
  }
  tra_feat[u*16 + j] = h;
}

// ------- fused pe + T: ep = edge@W^T+b; Tt[v][n] = (ep@(E2.E1))^T; only t in [5,15] -------
__global__ __launch_bounds__(256) void k_peT(const float* __restrict__ edge,
                    const float* __restrict__ Wp, const float* __restrict__ bp,
                    const float* __restrict__ Wa, const float* __restrict__ ba,
                    const float* __restrict__ E1p, const float* __restrict__ E2p,
                    const float* __restrict__ E1a, const float* __restrict__ E2a,
                    float* __restrict__ epp, float* __restrict__ epa,
                    float* __restrict__ Ttp, float* __restrict__ Tta) {
  __shared__ float sM[64];
  __shared__ float sW[88];
  __shared__ float sb[8];
  int s = blockIdx.z, t = 5 + blockIdx.y;
  const float* E1 = s ? E1a : E1p;
  const float* E2 = s ? E2a : E2p;
  const float* W  = s ? Wa : Wp;
  const float* b  = s ? ba : bp;
  float* ep = (s ? epa : epp) + (size_t)t*N_E*8;
  float* Tt = (s ? Tta : Ttp) + (size_t)t*8*N_E;
  int tid = threadIdx.x;
  if (tid < 64) {
    int u = tid >> 3, v = tid & 7;
    float m = 0.f;
    #pragma unroll
    for (int o=0;o<8;o++) m += E2[t*8+o]*E1[(o*8+u)*8+v];
    sM[u*8+v] = m;
  }
  if (tid >= 64 && tid < 152) sW[tid-64] = W[tid-64];
  if (tid >= 152 && tid < 160) sb[tid-152] = b[tid-152];
  __syncthreads();
  int n = blockIdx.x*256 + tid;
  const float* e = edge + ((size_t)t*N_E + n)*11;
  float ev[11];
  #pragma unroll
  for (int k=0;k<11;k++) ev[k] = e[k];
  float epr[8];
  #pragma unroll
  for (int c=0;c<8;c++) {
    float acc = sb[c];
    #pragma unroll
    for (int k=0;k<11;k++) acc = fmaf(ev[k], sW[c*11+k], acc);
    epr[c] = acc;
  }
  float4* eo = (float4*)(ep + (size_t)n*8);
  eo[0] = make_float4(epr[0],epr[1],epr[2],epr[3]);
  eo[1] = make_float4(epr[4],epr[5],epr[6],epr[7]);
  #pragma unroll
  for (int v=0;v<8;v++) {
    float acc = 0.f;
    #pragma unroll
    for (int u=0;u<8;u++) acc = fmaf(epr[u], sM[u*8+v], acc);
    Tt[(size_t)v*N_E + n] = acc;   // coalesced across lanes
  }
}

// --- softmax denominator: Zb[s,t,n] += 256 + sum_{m in split} expm1t(relu(T[n].ep[m])) ---
__global__ __launch_bounds__(256) void k_stats(const float* __restrict__ Ttp, const float* __restrict__ Tta,
                        const float* __restrict__ epp, const float* __restrict__ epa,
                        float* __restrict__ Zb) {
  __shared__ float sE[256*8];   // 8 KiB
  int s = blockIdx.z, t = 5 + blockIdx.y;
  int ntile = blockIdx.x & 7, sp = blockIdx.x >> 3;
  int n = ntile*256 + threadIdx.x;
  const float* Tt = (s ? Tta : Ttp) + (size_t)t*8*N_E;
  const float* E = (s ? epa : epp) + (size_t)t*N_E*8;
  int tid = threadIdx.x;
  float tr[8];
  #pragma unroll
  for (int v=0;v<8;v++) tr[v] = Tt[(size_t)v*N_E + n];   // coalesced
  int m0 = sp*256;
  {
    const float4* ge = (const float4*)(E + (size_t)m0*8);
    float4* se = (float4*)sE;
    for (int i = tid; i < 512; i += 256) se[i] = ge[i];
  }
  __syncthreads();
  float qs = 0.f;
  #pragma unroll 4
  for (int m = 0; m < 256; m++) {
    float d = 0.f;
    #pragma unroll
    for (int v=0;v<8;v++) d = fmaf(sE[m*8+v], tr[v], d);
    qs += expm1t(fmaxf(d, 0.f));
  }
  atomicAdd(&Zb[((size_t)s*KT + t)*N_E + n], 256.f + qs);
}

// --- dilated causal conv + ReLU, /Z, bf16 out; layer 0 computes proj(load/svc) on the fly;
//     fused colsum via atomics into per-layer ysum region ---
__global__ __launch_bounds__(256) void k_conv(const float* __restrict__ xp, const float* __restrict__ xa,
                       const float* __restrict__ loadx, const float* __restrict__ svcx,
                       const float* __restrict__ prWp, const float* __restrict__ prbp,
                       const float* __restrict__ prWa, const float* __restrict__ prba,
                       const float* __restrict__ Wtp, const float* __restrict__ Wta,
                       const float* __restrict__ btp, const float* __restrict__ bta,
                       const float* __restrict__ Zg,
                       unsigned short* __restrict__ yp, unsigned short* __restrict__ ya,
                       float* __restrict__ ysumL,
                       int layer, int dd, int tbase, int tstep) {
  __shared__ float sW[3*32*32];
  __shared__ float sX[8][3][32];
  __shared__ float rsum[256];
  __shared__ float sPW[96];
  __shared__ float sPb[32];
  int s = blockIdx.z;
  int t = tbase + blockIdx.y*tstep;
  const float* x  = s ? xa : xp;
  const float* Wt = (s ? Wta : Wtp) + (size_t)layer*3*32*32;
  const float* bt = (s ? bta : btp) + layer*32;
  unsigned short* y = s ? ya : yp;
  int tid = threadIdx.x;
  if (layer == 0) {
    if (tid < 96) sPW[tid] = (s ? prWa : prWp)[tid];
    else if (tid < 128) sPb[tid-96] = (s ? prba : prbp)[tid-96];
    __syncthreads();
  }
  for (int i = tid; i < 3*32*32; i += 256) sW[i] = Wt[i];
  int n0 = blockIdx.x*8;
  if (layer == 0) {
    const float* inx = s ? svcx : loadx;
    for (int i = tid; i < 768; i += 256) {
      int f = i & 31; int nn = (i>>5)&7; int j = i >> 8;
      int tt = t - (2-j)*dd;
      float v = 0.f;
      if (tt >= 0) {
        const float* ip = inx + ((size_t)tt*N_E + n0+nn)*3;
        v = sPb[f];
        v = fmaf(ip[0], sPW[f*3+0], v);
        v = fmaf(ip[1], sPW[f*3+1], v);
        v = fmaf(ip[2], sPW[f*3+2], v);
      }
      sX[nn][j][f] = v;
    }
  } else {
    for (int i = tid; i < 768; i += 256) {
      int f = i & 31; int nn = (i>>5)&7; int j = i >> 8;
      int tt = t - (2-j)*dd;
      sX[nn][j][f] = (tt >= 0) ? x[((size_t)tt*N_E + n0+nn)*32 + f] : 0.f;
    }
  }
  __syncthreads();
  int g = tid & 31, nn = tid >> 5;
  float acc = bt[g];
  #pragma unroll
  for (int j=0;j<3;j++)
    #pragma unroll
    for (int f=0;f<32;f++) acc += sX[nn][j][f]*sW[(j*32+f)*32+g];
  float zi = 1.0f / Zg[((size_t)s*KT + t)*N_E + n0+nn];
  float val = fmaxf(acc, 0.f)*zi;
  y[((size_t)t*N_E + n0+nn)*32 + g] = (unsigned short)f2bf(val);
  rsum[tid] = val;
  __syncthreads();
  if (tid < 32) {
    float a = 0.f;
    #pragma unroll
    for (int k=0;k<8;k++) a += rsum[tid + 32*k];
    atomicAdd(&ysumL[((size_t)s*gridDim.y + blockIdx.y)*32 + tid], a);
  }
}

// --------- MFMA mixing, double-buffered LDS; each wave owns TWO 16-m blocks (m0, m0+64),
// sharing the T broadcast reads and the Y B-fragments between them (halves LDS instrs/q) ---------
__global__ __launch_bounds__(256) void k_mixm(const float* __restrict__ Ttp, const float* __restrict__ Tta,
                      const float* __restrict__ epp, const float* __restrict__ epa,
                      const unsigned short* __restrict__ ybp, const unsigned short* __restrict__ yba,
                      float* __restrict__ part,
                      int tbase, int tstep, int nt, int nsplit) {
  __shared__ float sTt[2][8*132];             // 2 x 4.2 KiB
  __shared__ unsigned short sYb[2][128*34];   // 2 x 8.5 KiB
  int s = blockIdx.z, ty = blockIdx.y;
  int t = tbase + ty*tstep;
  int mtile = blockIdx.x & 15, split = blockIdx.x >> 4;
  int tid = threadIdx.x;
  int w = tid >> 6, lane = tid & 63;
  int g = lane >> 4, fc = lane & 15;
  int m0 = mtile*128 + w*16;                  // second m-block at m0+64
  const float* Tt = (s ? Tta : Ttp) + (size_t)t*8*N_E;
  const float* ep = (s ? epa : epp) + (size_t)t*N_E*8;
  const unsigned short* yb = (s ? yba : ybp) + (size_t)t*N_E*32;
  float er0[8], er1[8];
  {
    const float4* gep = (const float4*)(ep + (size_t)(m0 + fc)*8);
    float4 a = gep[0], b = gep[1];
    er0[0]=a.x; er0[1]=a.y; er0[2]=a.z; er0[3]=a.w;
    er0[4]=b.x; er0[5]=b.y; er0[6]=b.z; er0[7]=b.w;
    const float4* gep1 = (const float4*)(ep + (size_t)(m0 + 64 + fc)*8);
    float4 c = gep1[0], d = gep1[1];
    er1[0]=c.x; er1[1]=c.y; er1[2]=c.z; er1[3]=c.w;
    er1[4]=d.x; er1[5]=d.y; er1[6]=d.z; er1[7]=d.w;
  }
  f32x4 accA0 = {0.f,0.f,0.f,0.f}, accA1 = {0.f,0.f,0.f,0.f};
  f32x4 accB0 = {0.f,0.f,0.f,0.f}, accB1 = {0.f,0.f,0.f,0.f};
  int n0 = split*(N_E/nsplit);
  int nc = (N_E/nsplit)/128;                 // chunks
  int tv = tid >> 5, tc = tid & 31;          // T-stage coords
  float4 tReg, yR0, yR1;
  {
    tReg = *(const float4*)(Tt + (size_t)tv*N_E + n0 + tc*4);
    const float4* gy = (const float4*)(yb + (size_t)n0*32);
    yR0 = gy[tid]; yR1 = gy[tid + 256];
  }
  for (int ci = 0; ci < nc; ci++) {
    int buf = ci & 1;
    *(float4*)&sTt[buf][tv*132 + tc*4] = tReg;
    {
      union { float4 f; unsigned u[4]; } cv;
      cv.f = yR0;
      unsigned* d0 = (unsigned*)&sYb[buf][(tid>>2)*34 + (tid&3)*8];
      d0[0]=cv.u[0]; d0[1]=cv.u[1]; d0[2]=cv.u[2]; d0[3]=cv.u[3];
      cv.f = yR1;
      unsigned* d1 = (unsigned*)&sYb[buf][(64 + (tid>>2))*34 + (tid&3)*8];
      d1[0]=cv.u[0]; d1[1]=cv.u[1]; d1[2]=cv.u[2]; d1[3]=cv.u[3];
    }
    if (ci + 1 < nc) {   // issue next chunk's loads; full compute phase hides them
      int c1 = n0 + (ci+1)*128;
      tReg = *(const float4*)(Tt + (size_t)tv*N_E + c1 + tc*4);
      const float4* gy = (const float4*)(yb + (size_t)c1*32);
      yR0 = gy[tid]; yR1 = gy[tid + 256];
    }
    __syncthreads();
    #pragma unroll
    for (int sub = 0; sub < 4; sub++) {
      int rbase = sub*32 + g*8;
      f32x4 dA0 = {0.f,0.f,0.f,0.f}, dB0 = {0.f,0.f,0.f,0.f};
      f32x4 dA1 = {0.f,0.f,0.f,0.f}, dB1 = {0.f,0.f,0.f,0.f};
      #pragma unroll
      for (int v=0; v<8; v++) {
        const f32x4* tvp = (const f32x4*)&sTt[buf][v*132 + rbase];  // broadcast, 16B-aligned
        f32x4 ta = tvp[0], tb = tvp[1];
        float e0 = er0[v], e1 = er1[v];
        dA0 += ta * e0;  dB0 += tb * e0;
        dA1 += ta * e1;  dB1 += tb * e1;
      }
      short8 af0, af1;
      #pragma unroll
      for (int i=0;i<4;i++) af0[i]   = f2bf(expm1t(fmaxf(dA0[i], 0.f)));
      #pragma unroll
      for (int i=0;i<4;i++) af0[4+i] = f2bf(expm1t(fmaxf(dB0[i], 0.f)));
      #pragma unroll
      for (int i=0;i<4;i++) af1[i]   = f2bf(expm1t(fmaxf(dA1[i], 0.f)));
      #pragma unroll
      for (int i=0;i<4;i++) af1[4+i] = f2bf(expm1t(fmaxf(dB1[i], 0.f)));
      short8 bf0, bf1;   // shared B-fragments (same Y for both m-blocks)
      #pragma unroll
      for (int i=0;i<8;i++) {
        int row = (rbase + i)*34;
        bf0[i] = (short)sYb[buf][row + fc];
        bf1[i] = (short)sYb[buf][row + 16 + fc];
      }
      accA0 = __builtin_amdgcn_mfma_f32_16x16x32_bf16(af0, bf0, accA0, 0, 0, 0);
      accA1 = __builtin_amdgcn_mfma_f32_16x16x32_bf16(af0, bf1, accA1, 0, 0, 0);
      accB0 = __builtin_amdgcn_mfma_f32_16x16x32_bf16(af1, bf0, accB0, 0, 0, 0);
      accB1 = __builtin_amdgcn_mfma_f32_16x16x32_bf16(af1, bf1, accB1, 0, 0, 0);
    }
  }
  float* pb = part + (size_t)((s*nt + ty)*nsplit + split)*(N_E*32);
  #pragma unroll
  for (int r=0;r<4;r++) {
    pb[(size_t)(m0 + g*4 + r)*32 + fc]           = accA0[r];
    pb[(size_t)(m0 + g*4 + r)*32 + 16 + fc]      = accA1[r];
    pb[(size_t)(m0 + 64 + g*4 + r)*32 + fc]      = accB0[r];
    pb[(size_t)(m0 + 64 + g*4 + r)*32 + 16 + fc] = accB1[r];
  }
}

// ---------------- reduce nsplit partials + ysum + Wg + bias + ReLU ----------------
__global__ __launch_bounds__(256) void k_wg(const float* __restrict__ part,
                     const float* __restrict__ ysumL,
                     const float* __restrict__ Wgp, const float* __restrict__ Wga,
                     const float* __restrict__ bgp, const float* __restrict__ bga,
                     float* __restrict__ xop, float* __restrict__ xoa,
                     int layer, int tbase, int tstep, int nt, int nsplit) {
  __shared__ float sX[8*32];
  __shared__ float sWg[32*32];
  __shared__ float sBg[32];
  int s = blockIdx.z, ty = blockIdx.y;
  int t = tbase + ty*tstep;
  int m0 = blockIdx.x*8;
  const float* Wg = (s ? Wga : Wgp) + (size_t)layer*1024;
  const float* bg = (s ? bga : bgp) + layer*32;
  int tid = threadIdx.x;
  for (int i = tid; i < 1024; i += 256) sWg[i] = Wg[i];
  if (tid < 32) sBg[tid] = bg[tid];
  {
    int mm = tid >> 5, f = tid & 31;
    const float* p = part + (size_t)((s*nt + ty)*nsplit)*(N_E*32) + (size_t)(m0+mm)*32 + f;
    float a = ysumL[((size_t)s*nt + ty)*32 + f];
    for (int sp = 0; sp < nsplit; sp++) a += p[(size_t)sp*(N_E*32)];
    sX[mm*32+f] = a;
  }
  __syncthreads();
  int mm = tid >> 5, g = tid & 31;
  float a = sBg[g];
  #pragma unroll
  for (int f=0;f<32;f++) a += sX[mm*32+f]*sWg[f*32+g];
  (s ? xoa : xop)[((size_t)t*N_E + m0+mm)*32 + g] = fmaxf(a, 0.f);
}

// ---------------- fused gather + 6-layer MLP head, LDS-resident transposed weights ----------------
__global__ __launch_bounds__(64) void k_mlp(const int* __restrict__ info,
    const float* __restrict__ tf, const float* __restrict__ fpp, const float* __restrict__ fpa,
    const float* __restrict__ se, const float* __restrict__ ve,
    const float* __restrict__ W0, const float* __restrict__ b0,
    const float* __restrict__ W1, const float* __restrict__ b1,
    const float* __restrict__ W2, const float* __restrict__ b2,
    const float* __restrict__ W3, const float* __restrict__ b3,
    const float* __restrict__ W4, const float* __restrict__ b4,
    const float* __restrict__ W5, const float* __restrict__ b5,
    float* __restrict__ out) {
  __shared__ float sW0t[112*64];   // [k][g] transposed, 28 KiB
  __shared__ float sW1t[64*32];
  __shared__ float sW2t[32*16];
  __shared__ float sW3t[16*8];
  __shared__ float sW4t[8*4];
  __shared__ float sW5[4];
  __shared__ float sB0[64];
  __shared__ float sB1[32];
  __shared__ float sB2[16];
  __shared__ float sB3[8];
  __shared__ float sB4[4];
  __shared__ float sB5[1];
  int tid = threadIdx.x;
  for (int i = tid; i < 1792; i += 64) {        // W0: 64x112 floats, f4 along k
    float4 v = ((const float4*)W0)[i];
    int g = i / 28, kq = (i % 28)*4;
    sW0t[(kq+0)*64+g]=v.x; sW0t[(kq+1)*64+g]=v.y; sW0t[(kq+2)*64+g]=v.z; sW0t[(kq+3)*64+g]=v.w;
  }
  for (int i = tid; i < 2048; i += 64) sW1t[(i&63)*32 + (i>>6)] = W1[i];   // W1: 32x64
  for (int i = tid; i < 512; i += 64)  sW2t[(i&31)*16 + (i>>5)] = W2[i];   // W2: 16x32
  for (int i = tid; i < 128; i += 64)  sW3t[(i&15)*8  + (i>>4)] = W3[i];   // W3: 8x16
  if (tid < 32) sW4t[(tid&7)*4 + (tid>>3)] = W4[tid];                      // W4: 4x8
  if (tid < 4)  sW5[tid] = W5[tid];
  if (tid < 64) sB0[tid] = b0[tid];
  if (tid < 32) sB1[tid] = b1[tid];
  if (tid < 16) sB2[tid] = b2[tid];
  if (tid < 8)  sB3[tid] = b3[tid];
  if (tid < 4)  sB4[tid] = b4[tid];
  if (tid == 0) sB5[0] = b5[0];
  __syncthreads();

  int r = blockIdx.x*64 + tid;
  int4 ifo = ((const int4*)info)[r];
  int uid = ifo.x, eid = ifo.y, sid = ifo.z;

  f32x4 o0v[16];
  #pragma unroll
  for (int gq=0;gq<16;gq++) {
    o0v[gq][0]=sB0[gq*4]; o0v[gq][1]=sB0[gq*4+1]; o0v[gq][2]=sB0[gq*4+2]; o0v[gq][3]=sB0[gq*4+3];
  }
  {
    const float4* p = (const float4*)(tf + (size_t)uid*16);
    #pragma unroll
    for (int q=0;q<4;q++) {
      float4 v4 = p[q];
      #pragma unroll
      for (int j=0;j<4;j++) {
        float v = (&v4.x)[j];
        const f32x4* wc = (const f32x4*)&sW0t[(q*4+j)*64];
        #pragma unroll
        for (int gq=0;gq<16;gq++) o0v[gq] += wc[gq]*v;
      }
    }
  }
  {
    const float4* pp = (const float4*)(fpp + (size_t)eid*32);
    const float4* pa = (const float4*)(fpa + (size_t)eid*32);
    #pragma unroll
    for (int q=0;q<8;q++) {
      float4 a4 = pp[q], b4 = pa[q];
      #pragma unroll
      for (int j=0;j<4;j++) {
        float v = 0.5f*((&a4.x)[j] + (&b4.x)[j]);
        const f32x4* wc = (const f32x4*)&sW0t[(16+q*4+j)*64];
        #pragma unroll
        for (int gq=0;gq<16;gq++) o0v[gq] += wc[gq]*v;
      }
    }
  }
  {
    const float4* p = (const float4*)(se + (size_t)eid*32);
    #pragma unroll
    for (int q=0;q<8;q++) {
      float4 v4 = p[q];
      #pragma unroll
      for (int j=0;j<4;j++) {
        float v = (&v4.x)[j];
        const f32x4* wc = (const f32x4*)&sW0t[(48+q*4+j)*64];
        #pragma unroll
        for (int gq=0;gq<16;gq++) o0v[gq] += wc[gq]*v;
      }
    }
  }
  {
    const float4* p = (const float4*)(ve + (size_t)sid*32);
    #pragma unroll
    for (int q=0;q<8;q++) {
      float4 v4 = p[q];
      #pragma unroll
      for (int j=0;j<4;j++) {
        float v = (&v4.x)[j];
        const f32x4* wc = (const f32x4*)&sW0t[(80+q*4+j)*64];
        #pragma unroll
        for (int gq=0;gq<16;gq++) o0v[gq] += wc[gq]*v;
      }
    }
  }
  #pragma unroll
  for (int gq=0;gq<16;gq++) {
    #pragma unroll
    for (int j=0;j<4;j++) o0v[gq][j] = fmaxf(o0v[gq][j], 0.f);
  }
  f32x4 o1v[8];
  #pragma unroll
  for (int gq=0;gq<8;gq++) {
    o1v[gq][0]=sB1[gq*4]; o1v[gq][1]=sB1[gq*4+1]; o1v[gq][2]=sB1[gq*4+2]; o1v[gq][3]=sB1[gq*4+3];
  }
  #pragma unroll
  for (int k=0;k<64;k++) {
    float v = o0v[k>>2][k&3];
    const f32x4* wc = (const f32x4*)&sW1t[k*32];
    #pragma unroll
    for (int gq=0;gq<8;gq++) o1v[gq] += wc[gq]*v;
  }
  #pragma unroll
  for (int gq=0;gq<8;gq++) {
    #pragma unroll
    for (int j=0;j<4;j++) o1v[gq][j] = fmaxf(o1v[gq][j], 0.f);
  }
  float o2[16];
  #pragma unroll
  for (int g=0;g<16;g++) o2[g] = sB2[g];
  #pragma unroll
  for (int k=0;k<32;k++) {
    float v = o1v[k>>2][k&3];
    #pragma unroll
    for (int g=0;g<16;g++) o2[g] = fmaf(sW2t[k*16+g], v, o2[g]);
  }
  #pragma unroll
  for (int g=0;g<16;g++) o2[g] = fmaxf(o2[g], 0.f);
  float o3[8];
  #pragma unroll
  for (int g=0;g<8;g++) o3[g] = sB3[g];
  #pragma unroll
  for (int k=0;k<16;k++) {
    float v = o2[k];
    #pragma unroll
    for (int g=0;g<8;g++) o3[g] = fmaf(sW3t[k*8+g], v, o3[g]);
  }
  #pragma unroll
  for (int g=0;g<8;g++) o3[g] = fmaxf(o3[g], 0.f);
  float o4[4];
  #pragma unroll
  for (int g=0;g<4;g++) o4[g] = sB4[g];
  #pragma unroll
  for (int k=0;k<8;k++) {
    float v = o3[k];
    #pragma unroll
    for (int g=0;g<4;g++) o4[g] = fmaf(sW4t[k*4+g], v, o4[g]);
  }
  #pragma unroll
  for (int g=0;g<4;g++) o4[g] = fmaxf(o4[g], 0.f);
  float o5 = sB5[0];
  #pragma unroll
  for (int k=0;k<4;k++) o5 = fmaf(sW5[k], o4[k], o5);
  out[r] = o5;
}

extern "C" void kernel_launch(void* const* d_in, const int* in_sizes, int n_in,
                              void* d_out, int out_size, void* d_ws, size_t ws_size,
                              hipStream_t stream) {
  (void)in_sizes; (void)n_in; (void)out_size;
  const float* edge    = (const float*)d_in[0];
  const float* loadx   = (const float*)d_in[1];
  const float* svcx    = (const float*)d_in[2];
  const float* tra     = (const float*)d_in[3];
  const int*   info    = (const int*)d_in[4];
  const int*   srv_attr= (const int*)d_in[5];
  const int*   svc_attr= (const int*)d_in[6];
  const float* usr_tab = (const float*)d_in[7];
  const float* srv_tab0= (const float*)d_in[8];
  const float* srv_lvl = (const float*)d_in[9];
  const float* svc_tab0= (const float*)d_in[10];
  const float* svc_lvl = (const float*)d_in[11];
  const float* Wih = (const float*)d_in[12];
  const float* Whh = (const float*)d_in[13];
  const float* bih = (const float*)d_in[14];
  const float* bhh = (const float*)d_in[15];
  const float* E1p = (const float*)d_in[16];
  const float* E2p = (const float*)d_in[17];
  const float* peWp= (const float*)d_in[18];
  const float* pebp= (const float*)d_in[19];
  const float* E1a = (const float*)d_in[20];
  const float* E2a = (const float*)d_in[21];
  const float* peWa= (const float*)d_in[22];
  const float* peba= (const float*)d_in[23];
  const float* prWp= (const float*)d_in[24];
  const float* prbp= (const float*)d_in[25];
  const float* prWa= (const float*)d_in[26];
  const float* prba= (const float*)d_in[27];
  const float* Wtp = (const float*)d_in[28];
  const float* btp = (const float*)d_in[29];
  const float* Wgp = (const float*)d_in[30];
  const float* bgp = (const float*)d_in[31];
  const float* Wta = (const float*)d_in[32];
  const float* bta = (const float*)d_in[33];
  const float* Wga = (const float*)d_in[34];
  const float* bga = (const float*)d_in[35];
  const float* qW0 = (const float*)d_in[36]; const float* qb0 = (const float*)d_in[37];
  const float* qW1 = (const float*)d_in[38]; const float* qb1 = (const float*)d_in[39];
  const float* qW2 = (const float*)d_in[40]; const float* qb2 = (const float*)d_in[41];
  const float* qW3 = (const float*)d_in[42]; const float* qb3 = (const float*)d_in[43];
  const float* qW4 = (const float*)d_in[44]; const float* qb4 = (const float*)d_in[45];
  const float* qW5 = (const float*)d_in[46]; const float* qb5 = (const float*)d_in[47];
  float* out = (float*)d_out;

  // workspace layout (floats)
  float* ws = (float*)d_ws;
  size_t off = 0;
  float* srv_emb  = ws + off; off += (size_t)N_E*32;
  float* svc_emb  = ws + off; off += (size_t)N_SVC*32;
  float* tra_feat = ws + off; off += (size_t)N_U*16;
  float* epb      = ws + off; off += 2ull*KT*N_E*8;     // [s][t][n][8]
  float* Ttb      = ws + off; off += 2ull*TSTR;         // [s][t][8][n] transposed
  float* Zb       = ws + off; off += 2ull*KT*N_E;       // softmax denominator (atomic sum)
  float* ysumb    = ws + off; off += 4ull*2*11*32;      // per-layer colsum regions (atomic)
  size_t zclr_bytes = (2ull*KT*N_E + 4ull*2*11*32)*4;   // Zb + ysumb, contiguous
  float* xA       = ws + off; off += 2ull*STRX;
  float* xB       = ws + off; off += 2ull*STRX;
  unsigned short* ybf = (unsigned short*)(ws + off); off += (2ull*YSTR)/2;  // bf16 y'
  float* part     = ws + off;                           // rest of ws

  size_t slab = (size_t)N_E*32;                          // 65536 floats
  size_t avail_floats = (ws_size/4 > off) ? (ws_size/4 - off) : 0;
  int cap = (int)(avail_floats / slab);                  // part slabs available

  float* epp = epb;              float* epa = epb + (size_t)KT*N_E*8;
  float* Ttp = Ttb;              float* Tta = Ttb + (size_t)TSTR;
  unsigned short* ybp = ybf;     unsigned short* yba = ybf + (size_t)YSTR;

  hipMemsetAsync(Zb, 0, zclr_bytes, stream);   // zero Zb + all ysum regions (one launch)
  k_embed<<<384,256,0,stream>>>(srv_attr, svc_attr, srv_tab0, srv_lvl, svc_tab0, svc_lvl, srv_emb, svc_emb);
  k_lstm <<<256,256,0,stream>>>(usr_tab, tra, Wih, Whh, bih, bhh, tra_feat);
  k_peT  <<<dim3(8,11,2),256,0,stream>>>(edge, peWp, pebp, peWa, peba,
                                         E1p, E2p, E1a, E2a, epp, epa, Ttp, Tta);
  k_stats<<<dim3(64,11,2),256,0,stream>>>(Ttp, Tta, epp, epa, Zb);

  // per-layer active time sets (backward-propagated from t=15 output)
  const int Ldd[4]   = {1, 2, 1, 2};
  const int Ltb[4]   = {5, 9, 11, 15};
  const int Lts[4]   = {1, 1, 2, 1};
  const int Lnt[4]   = {11, 7, 3, 1};
  int Lsp[4]         = {4, 4, 8, 16};        // n-splits
  for (int i = 0; i < 4; i++)
    while (Lsp[i] > 1 && 2*Lnt[i]*Lsp[i] > cap) Lsp[i] >>= 1;

  const float* convin[4] = {xA /*unused for L0*/, xA, xB, xA};
  float*       wgout[4]  = {xA, xB, xA, xB};
  for (int i = 0; i < 4; i++) {
    float* ysumL = ysumb + (size_t)i*2*11*32;
    k_conv<<<dim3(256, Lnt[i], 2), 256, 0, stream>>>(
        convin[i], convin[i] + STRX, loadx, svcx, prWp, prbp, prWa, prba,
        Wtp, Wta, btp, bta, Zb, ybp, yba, ysumL, i, Ldd[i], Ltb[i], Lts[i]);
    k_mixm<<<dim3(16*Lsp[i], Lnt[i], 2), 256, 0, stream>>>(
        Ttp, Tta, epp, epa, ybp, yba, part, Ltb[i], Lts[i], Lnt[i], Lsp[i]);
    k_wg<<<dim3(256, Lnt[i], 2), 256, 0, stream>>>(
        part, ysumL, Wgp, Wga, bgp, bga, wgout[i], wgout[i] + STRX, i, Ltb[i], Lts[i], Lnt[i], Lsp[i]);
  }
  // final stream features at t=15 live in xB (layer 3 output)
  const float* fpp = xB + (size_t)15*N_E*32;
  const float* fpa = xB + STRX + (size_t)15*N_E*32;

  k_mlp<<<128,64,0,stream>>>(info, tra_feat, fpp, fpa, srv_emb, svc_emb,
                             qW0, qb0, qW1, qb1, qW2, qb2, qW3, qb3, qW4, qb4, qW5, qb5, out);
}

// Round 11
// 421.041 us; speedup vs baseline: 1.5743x; 1.1207x over previous
//
#include <hip/hip_runtime.h>
#include <math.h>

#define N_E 2048
#define N_U 4096
#define N_SVC 1024
#define KT 16
#define STRX (KT*N_E*32)   // per-stream x buffer stride (floats)
#define YSTR (KT*N_E*32)   // per-stream y buffer stride (shorts)
#define TSTR (KT*8*N_E)    // per-stream T^T stride (floats)

typedef __attribute__((ext_vector_type(8))) short short8;   // 8 bf16 (4 VGPRs)
typedef __attribute__((ext_vector_type(4))) float f32x4;

__device__ __forceinline__ float sigf(float x){ return 1.0f/(1.0f+__expf(-x)); }
__device__ __forceinline__ float tanhfast(float x){ return 1.0f - 2.0f/(__expf(2.0f*x)+1.0f); }
__device__ __forceinline__ short f2bf(float f){
  union { float f; unsigned u; } x; x.f = f;
  unsigned r = x.u + 0x7FFFu + ((x.u >> 16) & 1u);
  return (short)(r >> 16);
}
__device__ __forceinline__ short f2bf_trunc(float f){
  union { float f; unsigned u; } x; x.f = f;
  return (short)(x.u >> 16);
}
// expm1 2-term: rel err d^2/6 (<3e-7 abs for d<0.05 here). Used identically in
// stats (denominator) and mixm (numerator) -> softmax rows still sum to ~1 exactly.
__device__ __forceinline__ float expm1t(float d){
  return d*fmaf(d, 0.5f, 1.f);
}
__device__ __forceinline__ f32x4 shfl4(f32x4 v, int src){
  f32x4 r;
  r[0]=__shfl(v[0],src); r[1]=__shfl(v[1],src);
  r[2]=__shfl(v[2],src); r[3]=__shfl(v[3],src);
  return r;
}

// ---------------- embeddings: srv_emb (2048x32), svc_emb (1024x32) ----------------
__global__ void k_embed(const int* __restrict__ srv_attr, const int* __restrict__ svc_attr,
                        const float* __restrict__ srv_tab0, const float* __restrict__ srv_lvl,
                        const float* __restrict__ svc_tab0, const float* __restrict__ svc_lvl,
                        float* __restrict__ srv_emb, float* __restrict__ svc_emb) {
  int idx = blockIdx.x*256 + threadIdx.x;       // (2048+1024) rows * 32 cols
  int r = idx >> 5, c = idx & 31;
  int seg = c >> 3, cc = c & 7;
  if (r < N_E) {
    int a = srv_attr[r*4 + seg];
    srv_emb[r*32 + c] = (seg==0) ? srv_tab0[a*8+cc] : srv_lvl[((seg-1)*10 + a)*8 + cc];
  } else {
    int r2 = r - N_E;
    if (r2 < N_SVC) {
      int a = svc_attr[r2*4 + seg];
      svc_emb[r2*32 + c] = (seg==0) ? svc_tab0[a*8+cc] : svc_lvl[((seg-1)*10 + a)*8 + cc];
    }
  }
}

// ---------------- LSTM: 16 lanes per user, lane j owns hidden unit j ----------------
__global__ __launch_bounds__(256) void k_lstm(const float* __restrict__ usr_tab, const float* __restrict__ tra,
                       const float* __restrict__ Wih, const float* __restrict__ Whh,
                       const float* __restrict__ bih, const float* __restrict__ bhh,
                       float* __restrict__ tra_feat) {
  __shared__ float sWih[64*12];
  __shared__ float sWhh[64*16];
  __shared__ float sB[64];
  int tid = threadIdx.x;
  for (int i = tid; i < 64*12; i += 256) sWih[i] = Wih[i];
  for (int i = tid; i < 64*16; i += 256) sWhh[i] = Whh[i];
  if (tid < 64) sB[tid] = bih[tid] + bhh[tid];
  __syncthreads();
  int j  = tid & 15;
  int u  = blockIdx.x*16 + (tid >> 4);
  float xe[8];
  #pragma unroll
  for (int k=0;k<8;k++) xe[k] = usr_tab[u*8+k];
  float h = 0.f, c = 0.f;
  for (int t=0;t<KT;t++) {
    float gi = sB[j], gf = sB[16+j], gg = sB[32+j], go = sB[48+j];
    #pragma unroll
    for (int k=0;k<8;k++) {
      float v = xe[k];
      gi += sWih[j*12+k]*v;      gf += sWih[(16+j)*12+k]*v;
      gg += sWih[(32+j)*12+k]*v; go += sWih[(48+j)*12+k]*v;
    }
    #pragma unroll
    for (int k=0;k<4;k++) {
      float v = tra[((size_t)t*N_U + u)*4 + k];
      gi += sWih[j*12+8+k]*v;      gf += sWih[(16+j)*12+8+k]*v;
      gg += sWih[(32+j)*12+8+k]*v; go += sWih[(48+j)*12+8+k]*v;
    }
    #pragma unroll
    for (int jj=0;jj<16;jj++) {
      float hv = __shfl(h, jj, 16);
      gi += sWhh[j*16+jj]*hv;      gf += sWhh[(16+j)*16+jj]*hv;
      gg += sWhh[(32+j)*16+jj]*hv; go += sWhh[(48+j)*16+jj]*hv;
    }
    c = sigf(gf)*c + sigf(gi)*tanhfast(gg);
    h = sigf(go)*tanhfast(c);
  }
  tra_feat[u*16 + j] = h;
}

// ------- fused pe + T: ep = edge@W^T+b; Tt[v][n] = (ep@(E2.E1))^T; only t in [5,15] -------
__global__ __launch_bounds__(256) void k_peT(const float* __restrict__ edge,
                    const float* __restrict__ Wp, const float* __restrict__ bp,
                    const float* __restrict__ Wa, const float* __restrict__ ba,
                    const float* __restrict__ E1p, const float* __restrict__ E2p,
                    const float* __restrict__ E1a, const float* __restrict__ E2a,
                    float* __restrict__ epp, float* __restrict__ epa,
                    float* __restrict__ Ttp, float* __restrict__ Tta) {
  __shared__ float sM[64];
  __shared__ float sW[88];
  __shared__ float sb[8];
  int s = blockIdx.z, t = 5 + blockIdx.y;
  const float* E1 = s ? E1a : E1p;
  const float* E2 = s ? E2a : E2p;
  const float* W  = s ? Wa : Wp;
  const float* b  = s ? ba : bp;
  float* ep = (s ? epa : epp) + (size_t)t*N_E*8;
  float* Tt = (s ? Tta : Ttp) + (size_t)t*8*N_E;
  int tid = threadIdx.x;
  if (tid < 64) {
    int u = tid >> 3, v = tid & 7;
    float m = 0.f;
    #pragma unroll
    for (int o=0;o<8;o++) m += E2[t*8+o]*E1[(o*8+u)*8+v];
    sM[u*8+v] = m;
  }
  if (tid >= 64 && tid < 152) sW[tid-64] = W[tid-64];
  if (tid >= 152 && tid < 160) sb[tid-152] = b[tid-152];
  __syncthreads();
  int n = blockIdx.x*256 + tid;
  const float* e = edge + ((size_t)t*N_E + n)*11;
  float ev[11];
  #pragma unroll
  for (int k=0;k<11;k++) ev[k] = e[k];
  float epr[8];
  #pragma unroll
  for (int c=0;c<8;c++) {
    float acc = sb[c];
    #pragma unroll
    for (int k=0;k<11;k++) acc = fmaf(ev[k], sW[c*11+k], acc);
    epr[c] = acc;
  }
  float4* eo = (float4*)(ep + (size_t)n*8);
  eo[0] = make_float4(epr[0],epr[1],epr[2],epr[3]);
  eo[1] = make_float4(epr[4],epr[5],epr[6],epr[7]);
  #pragma unroll
  for (int v=0;v<8;v++) {
    float acc = 0.f;
    #pragma unroll
    for (int u=0;u<8;u++) acc = fmaf(epr[u], sM[u*8+v], acc);
    Tt[(size_t)v*N_E + n] = acc;   // coalesced across lanes
  }
}

// --- softmax denominator: Zb[s,t,n] += 256 + sum_{m in split} expm1t(relu(T[n].ep[m])) ---
__global__ __launch_bounds__(256) void k_stats(const float* __restrict__ Ttp, const float* __restrict__ Tta,
                        const float* __restrict__ epp, const float* __restrict__ epa,
                        float* __restrict__ Zb) {
  __shared__ float sE[256*8];   // 8 KiB
  int s = blockIdx.z, t = 5 + blockIdx.y;
  int ntile = blockIdx.x & 7, sp = blockIdx.x >> 3;
  int n = ntile*256 + threadIdx.x;
  const float* Tt = (s ? Tta : Ttp) + (size_t)t*8*N_E;
  const float* E = (s ? epa : epp) + (size_t)t*N_E*8;
  int tid = threadIdx.x;
  float tr[8];
  #pragma unroll
  for (int v=0;v<8;v++) tr[v] = Tt[(size_t)v*N_E + n];   // coalesced
  int m0 = sp*256;
  {
    const float4* ge = (const float4*)(E + (size_t)m0*8);
    float4* se = (float4*)sE;
    for (int i = tid; i < 512; i += 256) se[i] = ge[i];
  }
  __syncthreads();
  float qs = 0.f;
  #pragma unroll 4
  for (int m = 0; m < 256; m++) {
    float d = 0.f;
    #pragma unroll
    for (int v=0;v<8;v++) d = fmaf(sE[m*8+v], tr[v], d);
    qs += expm1t(fmaxf(d, 0.f));
  }
  atomicAdd(&Zb[((size_t)s*KT + t)*N_E + n], 256.f + qs);
}

// --- dilated causal conv + ReLU, /Z, bf16 out; layer 0 computes proj(load/svc) on the fly;
//     fused colsum via atomics into per-layer ysum region ---
__global__ __launch_bounds__(256) void k_conv(const float* __restrict__ xp, const float* __restrict__ xa,
                       const float* __restrict__ loadx, const float* __restrict__ svcx,
                       const float* __restrict__ prWp, const float* __restrict__ prbp,
                       const float* __restrict__ prWa, const float* __restrict__ prba,
                       const float* __restrict__ Wtp, const float* __restrict__ Wta,
                       const float* __restrict__ btp, const float* __restrict__ bta,
                       const float* __restrict__ Zg,
                       unsigned short* __restrict__ yp, unsigned short* __restrict__ ya,
                       float* __restrict__ ysumL,
                       int layer, int dd, int tbase, int tstep) {
  __shared__ float sW[3*32*32];
  __shared__ float sX[8][3][32];
  __shared__ float rsum[256];
  __shared__ float sPW[96];
  __shared__ float sPb[32];
  int s = blockIdx.z;
  int t = tbase + blockIdx.y*tstep;
  const float* x  = s ? xa : xp;
  const float* Wt = (s ? Wta : Wtp) + (size_t)layer*3*32*32;
  const float* bt = (s ? bta : btp) + layer*32;
  unsigned short* y = s ? ya : yp;
  int tid = threadIdx.x;
  if (layer == 0) {
    if (tid < 96) sPW[tid] = (s ? prWa : prWp)[tid];
    else if (tid < 128) sPb[tid-96] = (s ? prba : prbp)[tid-96];
    __syncthreads();
  }
  for (int i = tid; i < 3*32*32; i += 256) sW[i] = Wt[i];
  int n0 = blockIdx.x*8;
  if (layer == 0) {
    const float* inx = s ? svcx : loadx;
    for (int i = tid; i < 768; i += 256) {
      int f = i & 31; int nn = (i>>5)&7; int j = i >> 8;
      int tt = t - (2-j)*dd;
      float v = 0.f;
      if (tt >= 0) {
        const float* ip = inx + ((size_t)tt*N_E + n0+nn)*3;
        v = sPb[f];
        v = fmaf(ip[0], sPW[f*3+0], v);
        v = fmaf(ip[1], sPW[f*3+1], v);
        v = fmaf(ip[2], sPW[f*3+2], v);
      }
      sX[nn][j][f] = v;
    }
  } else {
    for (int i = tid; i < 768; i += 256) {
      int f = i & 31; int nn = (i>>5)&7; int j = i >> 8;
      int tt = t - (2-j)*dd;
      sX[nn][j][f] = (tt >= 0) ? x[((size_t)tt*N_E + n0+nn)*32 + f] : 0.f;
    }
  }
  __syncthreads();
  int g = tid & 31, nn = tid >> 5;
  float acc = bt[g];
  #pragma unroll
  for (int j=0;j<3;j++)
    #pragma unroll
    for (int f=0;f<32;f++) acc += sX[nn][j][f]*sW[(j*32+f)*32+g];
  float zi = 1.0f / Zg[((size_t)s*KT + t)*N_E + n0+nn];
  float val = fmaxf(acc, 0.f)*zi;
  y[((size_t)t*N_E + n0+nn)*32 + g] = (unsigned short)f2bf(val);
  rsum[tid] = val;
  __syncthreads();
  if (tid < 32) {
    float a = 0.f;
    #pragma unroll
    for (int k=0;k<8;k++) a += rsum[tid + 32*k];
    atomicAdd(&ysumL[((size_t)s*gridDim.y + blockIdx.y)*32 + tid], a);
  }
}

// --------- MFMA mixing, double-buffered LDS; each wave owns TWO 16-m blocks (m0, m0+64),
// sharing the T broadcast reads and the Y B-fragments between them ---------
__global__ __launch_bounds__(256) void k_mixm(const float* __restrict__ Ttp, const float* __restrict__ Tta,
                      const float* __restrict__ epp, const float* __restrict__ epa,
                      const unsigned short* __restrict__ ybp, const unsigned short* __restrict__ yba,
                      float* __restrict__ part,
                      int tbase, int tstep, int nt, int nsplit) {
  __shared__ float sTt[2][8*132];             // 2 x 4.2 KiB
  __shared__ unsigned short sYb[2][128*34];   // 2 x 8.5 KiB
  int s = blockIdx.z, ty = blockIdx.y;
  int t = tbase + ty*tstep;
  int mtile = blockIdx.x & 15, split = blockIdx.x >> 4;
  int tid = threadIdx.x;
  int w = tid >> 6, lane = tid & 63;
  int g = lane >> 4, fc = lane & 15;
  int m0 = mtile*128 + w*16;                  // second m-block at m0+64
  const float* Tt = (s ? Tta : Ttp) + (size_t)t*8*N_E;
  const float* ep = (s ? epa : epp) + (size_t)t*N_E*8;
  const unsigned short* yb = (s ? yba : ybp) + (size_t)t*N_E*32;
  float er0[8], er1[8];
  {
    const float4* gep = (const float4*)(ep + (size_t)(m0 + fc)*8);
    float4 a = gep[0], b = gep[1];
    er0[0]=a.x; er0[1]=a.y; er0[2]=a.z; er0[3]=a.w;
    er0[4]=b.x; er0[5]=b.y; er0[6]=b.z; er0[7]=b.w;
    const float4* gep1 = (const float4*)(ep + (size_t)(m0 + 64 + fc)*8);
    float4 c = gep1[0], d = gep1[1];
    er1[0]=c.x; er1[1]=c.y; er1[2]=c.z; er1[3]=c.w;
    er1[4]=d.x; er1[5]=d.y; er1[6]=d.z; er1[7]=d.w;
  }
  f32x4 accA0 = {0.f,0.f,0.f,0.f}, accA1 = {0.f,0.f,0.f,0.f};
  f32x4 accB0 = {0.f,0.f,0.f,0.f}, accB1 = {0.f,0.f,0.f,0.f};
  int n0 = split*(N_E/nsplit);
  int nc = (N_E/nsplit)/128;                 // chunks
  int tv = tid >> 5, tc = tid & 31;          // T-stage coords
  float4 tReg, yR0, yR1;
  {
    tReg = *(const float4*)(Tt + (size_t)tv*N_E + n0 + tc*4);
    const float4* gy = (const float4*)(yb + (size_t)n0*32);
    yR0 = gy[tid]; yR1 = gy[tid + 256];
  }
  for (int ci = 0; ci < nc; ci++) {
    int buf = ci & 1;
    *(float4*)&sTt[buf][tv*132 + tc*4] = tReg;
    {
      union { float4 f; unsigned u[4]; } cv;
      cv.f = yR0;
      unsigned* d0 = (unsigned*)&sYb[buf][(tid>>2)*34 + (tid&3)*8];
      d0[0]=cv.u[0]; d0[1]=cv.u[1]; d0[2]=cv.u[2]; d0[3]=cv.u[3];
      cv.f = yR1;
      unsigned* d1 = (unsigned*)&sYb[buf][(64 + (tid>>2))*34 + (tid&3)*8];
      d1[0]=cv.u[0]; d1[1]=cv.u[1]; d1[2]=cv.u[2]; d1[3]=cv.u[3];
    }
    if (ci + 1 < nc) {   // issue next chunk's loads; full compute phase hides them
      int c1 = n0 + (ci+1)*128;
      tReg = *(const float4*)(Tt + (size_t)tv*N_E + c1 + tc*4);
      const float4* gy = (const float4*)(yb + (size_t)c1*32);
      yR0 = gy[tid]; yR1 = gy[tid + 256];
    }
    __syncthreads();
    #pragma unroll
    for (int sub = 0; sub < 4; sub++) {
      int rbase = sub*32 + g*8;
      f32x4 dA0 = {0.f,0.f,0.f,0.f}, dB0 = {0.f,0.f,0.f,0.f};
      f32x4 dA1 = {0.f,0.f,0.f,0.f}, dB1 = {0.f,0.f,0.f,0.f};
      #pragma unroll
      for (int v=0; v<8; v++) {
        const f32x4* tvp = (const f32x4*)&sTt[buf][v*132 + rbase];  // broadcast, 16B-aligned
        f32x4 ta = tvp[0], tb = tvp[1];
        float e0 = er0[v], e1 = er1[v];
        dA0 += ta * e0;  dB0 += tb * e0;
        dA1 += ta * e1;  dB1 += tb * e1;
      }
      short8 af0, af1;
      #pragma unroll
      for (int i=0;i<4;i++) af0[i]   = f2bf_trunc(expm1t(fmaxf(dA0[i], 0.f)));
      #pragma unroll
      for (int i=0;i<4;i++) af0[4+i] = f2bf_trunc(expm1t(fmaxf(dB0[i], 0.f)));
      #pragma unroll
      for (int i=0;i<4;i++) af1[i]   = f2bf_trunc(expm1t(fmaxf(dA1[i], 0.f)));
      #pragma unroll
      for (int i=0;i<4;i++) af1[4+i] = f2bf_trunc(expm1t(fmaxf(dB1[i], 0.f)));
      short8 bf0, bf1;   // shared B-fragments (same Y for both m-blocks)
      #pragma unroll
      for (int i=0;i<8;i++) {
        int row = (rbase + i)*34;
        bf0[i] = (short)sYb[buf][row + fc];
        bf1[i] = (short)sYb[buf][row + 16 + fc];
      }
      accA0 = __builtin_amdgcn_mfma_f32_16x16x32_bf16(af0, bf0, accA0, 0, 0, 0);
      accA1 = __builtin_amdgcn_mfma_f32_16x16x32_bf16(af0, bf1, accA1, 0, 0, 0);
      accB0 = __builtin_amdgcn_mfma_f32_16x16x32_bf16(af1, bf0, accB0, 0, 0, 0);
      accB1 = __builtin_amdgcn_mfma_f32_16x16x32_bf16(af1, bf1, accB1, 0, 0, 0);
    }
  }
  float* pb = part + (size_t)((s*nt + ty)*nsplit + split)*(N_E*32);
  #pragma unroll
  for (int r=0;r<4;r++) {
    pb[(size_t)(m0 + g*4 + r)*32 + fc]           = accA0[r];
    pb[(size_t)(m0 + g*4 + r)*32 + 16 + fc]      = accA1[r];
    pb[(size_t)(m0 + 64 + g*4 + r)*32 + fc]      = accB0[r];
    pb[(size_t)(m0 + 64 + g*4 + r)*32 + 16 + fc] = accB1[r];
  }
}

// ---------------- reduce nsplit partials + ysum + Wg + bias + ReLU ----------------
__global__ __launch_bounds__(256) void k_wg(const float* __restrict__ part,
                     const float* __restrict__ ysumL,
                     const float* __restrict__ Wgp, const float* __restrict__ Wga,
                     const float* __restrict__ bgp, const float* __restrict__ bga,
                     float* __restrict__ xop, float* __restrict__ xoa,
                     int layer, int tbase, int tstep, int nt, int nsplit) {
  __shared__ float sX[8*32];
  __shared__ float sWg[32*32];
  __shared__ float sBg[32];
  int s = blockIdx.z, ty = blockIdx.y;
  int t = tbase + ty*tstep;
  int m0 = blockIdx.x*8;
  const float* Wg = (s ? Wga : Wgp) + (size_t)layer*1024;
  const float* bg = (s ? bga : bgp) + layer*32;
  int tid = threadIdx.x;
  for (int i = tid; i < 1024; i += 256) sWg[i] = Wg[i];
  if (tid < 32) sBg[tid] = bg[tid];
  {
    int mm = tid >> 5, f = tid & 31;
    const float* p = part + (size_t)((s*nt + ty)*nsplit)*(N_E*32) + (size_t)(m0+mm)*32 + f;
    float a = ysumL[((size_t)s*nt + ty)*32 + f];
    for (int sp = 0; sp < nsplit; sp++) a += p[(size_t)sp*(N_E*32)];
    sX[mm*32+f] = a;
  }
  __syncthreads();
  int mm = tid >> 5, g = tid & 31;
  float a = sBg[g];
  #pragma unroll
  for (int f=0;f<32;f++) a += sX[mm*32+f]*sWg[f*32+g];
  (s ? xoa : xop)[((size_t)t*N_E + m0+mm)*32 + g] = fmaxf(a, 0.f);
}

// ------- fused gather + 6-layer MLP head: 4 lanes per row (split-K L0 + split-output L1+) -------
__global__ __launch_bounds__(128) void k_mlp(const int* __restrict__ info,
    const float* __restrict__ tf, const float* __restrict__ fpp, const float* __restrict__ fpa,
    const float* __restrict__ se, const float* __restrict__ ve,
    const float* __restrict__ W0, const float* __restrict__ b0,
    const float* __restrict__ W1, const float* __restrict__ b1,
    const float* __restrict__ W2, const float* __restrict__ b2,
    const float* __restrict__ W3, const float* __restrict__ b3,
    const float* __restrict__ W4, const float* __restrict__ b4,
    const float* __restrict__ W5, const float* __restrict__ b5,
    float* __restrict__ out) {
  __shared__ __attribute__((aligned(16))) float sW0t[112*68];  // [k][g], stride 68: j-groups spread banks
  __shared__ __attribute__((aligned(16))) float sW1t[64*32];   // [k][g]
  __shared__ __attribute__((aligned(16))) float sW2t[32*16];
  __shared__ __attribute__((aligned(16))) float sW3t[16*8];
  __shared__ __attribute__((aligned(16))) float sW4t[8*4];
  __shared__ float sW5v[4];
  __shared__ float sB0[64];
  __shared__ float sB1[32];
  __shared__ float sB2[16];
  __shared__ float sB3[8];
  __shared__ float sB4[4];
  __shared__ float sB5[1];
  int tid = threadIdx.x;
  for (int i = tid; i < 1792; i += 128) {        // W0: 64x112
    float4 v = ((const float4*)W0)[i];
    int g = i / 28, kq = (i % 28)*4;
    sW0t[(kq+0)*68 + g] = v.x;
    sW0t[(kq+1)*68 + g] = v.y;
    sW0t[(kq+2)*68 + g] = v.z;
    sW0t[(kq+3)*68 + g] = v.w;
  }
  for (int i = tid; i < 512; i += 128) {         // W1: 32x64
    float4 v = ((const float4*)W1)[i];
    int g = i >> 4, kq = (i & 15)*4;
    sW1t[(kq+0)*32+g]=v.x; sW1t[(kq+1)*32+g]=v.y; sW1t[(kq+2)*32+g]=v.z; sW1t[(kq+3)*32+g]=v.w;
  }
  {                                              // W2: 16x32 (128 f4)
    int i = tid;
    if (i < 128) {
      float4 v = ((const float4*)W2)[i];
      int g = i >> 3, kq = (i & 7)*4;
      sW2t[(kq+0)*16+g]=v.x; sW2t[(kq+1)*16+g]=v.y; sW2t[(kq+2)*16+g]=v.z; sW2t[(kq+3)*16+g]=v.w;
    }
  }
  if (tid < 128) sW3t[(tid&15)*8 + (tid>>4)] = W3[tid];   // W3: 8x16
  if (tid < 32)  sW4t[(tid&7)*4 + (tid>>3)] = W4[tid];    // W4: 4x8
  if (tid < 4)   sW5v[tid] = W5[tid];
  if (tid < 64) sB0[tid]=b0[tid];
  if (tid < 32) sB1[tid]=b1[tid];
  if (tid < 16) sB2[tid]=b2[tid];
  if (tid < 8)  sB3[tid]=b3[tid];
  if (tid < 4)  sB4[tid]=b4[tid];
  if (tid == 0) sB5[0]=b5[0];
  __syncthreads();

  int rl = tid >> 2, j = tid & 3;
  int lb = (tid & 63) & ~3;                 // wave-lane base of this row's 4-lane group
  int r = blockIdx.x*32 + rl;
  int4 ifo = ((const int4*)info)[r];
  int uid = ifo.x, eid = ifo.y, sid = ifo.z;

  // lane j loads input floats [28j, 28j+28) of the concatenated 112-vector
  float4 hk[7];
  if (j == 0) {
    const float4* p = (const float4*)(tf + (size_t)uid*16);
    hk[0]=p[0]; hk[1]=p[1]; hk[2]=p[2]; hk[3]=p[3];
    const float4* pp = (const float4*)(fpp + (size_t)eid*32);
    const float4* pa = (const float4*)(fpa + (size_t)eid*32);
    #pragma unroll
    for (int q=0;q<3;q++){ float4 a=pp[q], b=pa[q];
      hk[4+q] = make_float4(0.5f*(a.x+b.x),0.5f*(a.y+b.y),0.5f*(a.z+b.z),0.5f*(a.w+b.w)); }
  } else if (j == 1) {
    const float4* pp = (const float4*)(fpp + (size_t)eid*32);
    const float4* pa = (const float4*)(fpa + (size_t)eid*32);
    #pragma unroll
    for (int q=0;q<5;q++){ float4 a=pp[3+q], b=pa[3+q];
      hk[q] = make_float4(0.5f*(a.x+b.x),0.5f*(a.y+b.y),0.5f*(a.z+b.z),0.5f*(a.w+b.w)); }
    const float4* p = (const float4*)(se + (size_t)eid*32);
    hk[5]=p[0]; hk[6]=p[1];
  } else if (j == 2) {
    const float4* p = (const float4*)(se + (size_t)eid*32);
    #pragma unroll
    for (int q=0;q<6;q++) hk[q]=p[2+q];
    hk[6]=((const float4*)(ve + (size_t)sid*32))[0];
  } else {
    const float4* pv = (const float4*)(ve + (size_t)sid*32);
    #pragma unroll
    for (int q=0;q<7;q++) hk[q]=pv[1+q];
  }
  // layer 0: split-K partials (weight rows [28j, 28j+28) = exactly my loaded inputs)
  f32x4 o0[16];
  #pragma unroll
  for (int gq=0;gq<16;gq++) o0[gq]=(f32x4){0.f,0.f,0.f,0.f};
  const float* w0b = sW0t + 28*j*68;
  #pragma unroll
  for (int q=0;q<7;q++) {
    #pragma unroll
    for (int e=0;e<4;e++) {
      float v = (&hk[q].x)[e];
      const f32x4* row = (const f32x4*)(w0b + (q*4+e)*68);
      #pragma unroll
      for (int gq=0;gq<16;gq++) o0[gq] += row[gq]*v;
    }
  }
  // butterfly reduce across the 4 lanes, + bias + relu (full o0 replicated)
  #pragma unroll
  for (int gq=0;gq<16;gq++) {
    f32x4 v = o0[gq];
    #pragma unroll
    for (int c=0;c<4;c++) {
      float x = v[c];
      x += __shfl_xor(x, 1);
      x += __shfl_xor(x, 2);
      v[c] = fmaxf(x + sB0[gq*4+c], 0.f);
    }
    o0[gq] = v;
  }
  // layer 1: lane j computes outputs [8j, 8j+8)
  f32x4 o1a, o1b;
  #pragma unroll
  for (int c=0;c<4;c++){ o1a[c]=sB1[8*j+c]; o1b[c]=sB1[8*j+4+c]; }
  const float* w1b = sW1t + 8*j;
  #pragma unroll
  for (int k=0;k<64;k++) {
    float v = o0[k>>2][k&3];
    const f32x4* wp = (const f32x4*)(w1b + k*32);
    o1a += wp[0]*v; o1b += wp[1]*v;
  }
  #pragma unroll
  for (int c=0;c<4;c++){ o1a[c]=fmaxf(o1a[c],0.f); o1b[c]=fmaxf(o1b[c],0.f); }
  f32x4 o1f[8];                         // gather full o1 (32)
  #pragma unroll
  for (int q=0;q<8;q++) o1f[q] = shfl4((q&1)?o1b:o1a, lb | (q>>1));
  // layer 2: lane j computes outputs [4j, 4j+4)
  f32x4 o2;
  #pragma unroll
  for (int c=0;c<4;c++) o2[c]=sB2[4*j+c];
  const float* w2b = sW2t + 4*j;
  #pragma unroll
  for (int k=0;k<32;k++) o2 += *(const f32x4*)(w2b + k*16) * o1f[k>>2][k&3];
  #pragma unroll
  for (int c=0;c<4;c++) o2[c]=fmaxf(o2[c],0.f);
  f32x4 o2f[4];
  #pragma unroll
  for (int q=0;q<4;q++) o2f[q] = shfl4(o2, lb | q);
  // layer 3: lane j computes outputs 2j, 2j+1
  float o3a = sB3[2*j], o3b = sB3[2*j+1];
  #pragma unroll
  for (int k=0;k<16;k++) {
    float v = o2f[k>>2][k&3];
    o3a = fmaf(sW3t[k*8 + 2*j], v, o3a);
    o3b = fmaf(sW3t[k*8 + 2*j + 1], v, o3b);
  }
  o3a = fmaxf(o3a,0.f); o3b = fmaxf(o3b,0.f);
  float o3f[8];
  #pragma unroll
  for (int i2=0;i2<8;i2++) o3f[i2] = __shfl((i2&1)?o3b:o3a, lb | (i2>>1));
  // layer 4: lane j computes output j
  float o4 = sB4[j];
  #pragma unroll
  for (int k=0;k<8;k++) o4 = fmaf(sW4t[k*4 + j], o3f[k], o4);
  o4 = fmaxf(o4, 0.f);
  // layer 5
  float o5 = sB5[0];
  #pragma unroll
  for (int i2=0;i2<4;i2++) o5 = fmaf(sW5v[i2], __shfl(o4, lb | i2), o5);
  if (j == 0) out[r] = o5;
}

extern "C" void kernel_launch(void* const* d_in, const int* in_sizes, int n_in,
                              void* d_out, int out_size, void* d_ws, size_t ws_size,
                              hipStream_t stream) {
  (void)in_sizes; (void)n_in; (void)out_size;
  const float* edge    = (const float*)d_in[0];
  const float* loadx   = (const float*)d_in[1];
  const float* svcx    = (const float*)d_in[2];
  const float* tra     = (const float*)d_in[3];
  const int*   info    = (const int*)d_in[4];
  const int*   srv_attr= (const int*)d_in[5];
  const int*   svc_attr= (const int*)d_in[6];
  const float* usr_tab = (const float*)d_in[7];
  const float* srv_tab0= (const float*)d_in[8];
  const float* srv_lvl = (const float*)d_in[9];
  const float* svc_tab0= (const float*)d_in[10];
  const float* svc_lvl = (const float*)d_in[11];
  const float* Wih = (const float*)d_in[12];
  const float* Whh = (const float*)d_in[13];
  const float* bih = (const float*)d_in[14];
  const float* bhh = (const float*)d_in[15];
  const float* E1p = (const float*)d_in[16];
  const float* E2p = (const float*)d_in[17];
  const float* peWp= (const float*)d_in[18];
  const float* pebp= (const float*)d_in[19];
  const float* E1a = (const float*)d_in[20];
  const float* E2a = (const float*)d_in[21];
  const float* peWa= (const float*)d_in[22];
  const float* peba= (const float*)d_in[23];
  const float* prWp= (const float*)d_in[24];
  const float* prbp= (const float*)d_in[25];
  const float* prWa= (const float*)d_in[26];
  const float* prba= (const float*)d_in[27];
  const float* Wtp = (const float*)d_in[28];
  const float* btp = (const float*)d_in[29];
  const float* Wgp = (const float*)d_in[30];
  const float* bgp = (const float*)d_in[31];
  const float* Wta = (const float*)d_in[32];
  const float* bta = (const float*)d_in[33];
  const float* Wga = (const float*)d_in[34];
  const float* bga = (const float*)d_in[35];
  const float* qW0 = (const float*)d_in[36]; const float* qb0 = (const float*)d_in[37];
  const float* qW1 = (const float*)d_in[38]; const float* qb1 = (const float*)d_in[39];
  const float* qW2 = (const float*)d_in[40]; const float* qb2 = (const float*)d_in[41];
  const float* qW3 = (const float*)d_in[42]; const float* qb3 = (const float*)d_in[43];
  const float* qW4 = (const float*)d_in[44]; const float* qb4 = (const float*)d_in[45];
  const float* qW5 = (const float*)d_in[46]; const float* qb5 = (const float*)d_in[47];
  float* out = (float*)d_out;

  // workspace layout (floats)
  float* ws = (float*)d_ws;
  size_t off = 0;
  float* srv_emb  = ws + off; off += (size_t)N_E*32;
  float* svc_emb  = ws + off; off += (size_t)N_SVC*32;
  float* tra_feat = ws + off; off += (size_t)N_U*16;
  float* epb      = ws + off; off += 2ull*KT*N_E*8;     // [s][t][n][8]
  float* Ttb      = ws + off; off += 2ull*TSTR;         // [s][t][8][n] transposed
  float* Zb       = ws + off; off += 2ull*KT*N_E;       // softmax denominator (atomic sum)
  float* ysumb    = ws + off; off += 4ull*2*11*32;      // per-layer colsum regions (atomic)
  size_t zclr_bytes = (2ull*KT*N_E + 4ull*2*11*32)*4;   // Zb + ysumb, contiguous
  float* xA       = ws + off; off += 2ull*STRX;
  float* xB       = ws + off; off += 2ull*STRX;
  unsigned short* ybf = (unsigned short*)(ws + off); off += (2ull*YSTR)/2;  // bf16 y'
  float* part     = ws + off;                           // rest of ws

  size_t slab = (size_t)N_E*32;                          // 65536 floats
  size_t avail_floats = (ws_size/4 > off) ? (ws_size/4 - off) : 0;
  int cap = (int)(avail_floats / slab);                  // part slabs available

  float* epp = epb;              float* epa = epb + (size_t)KT*N_E*8;
  float* Ttp = Ttb;              float* Tta = Ttb + (size_t)TSTR;
  unsigned short* ybp = ybf;     unsigned short* yba = ybf + (size_t)YSTR;

  hipMemsetAsync(Zb, 0, zclr_bytes, stream);   // zero Zb + all ysum regions (one launch)
  k_embed<<<384,256,0,stream>>>(srv_attr, svc_attr, srv_tab0, srv_lvl, svc_tab0, svc_lvl, srv_emb, svc_emb);
  k_lstm <<<256,256,0,stream>>>(usr_tab, tra, Wih, Whh, bih, bhh, tra_feat);
  k_peT  <<<dim3(8,11,2),256,0,stream>>>(edge, peWp, pebp, peWa, peba,
                                         E1p, E2p, E1a, E2a, epp, epa, Ttp, Tta);
  k_stats<<<dim3(64,11,2),256,0,stream>>>(Ttp, Tta, epp, epa, Zb);

  // per-layer active time sets (backward-propagated from t=15 output)
  const int Ldd[4]   = {1, 2, 1, 2};
  const int Ltb[4]   = {5, 9, 11, 15};
  const int Lts[4]   = {1, 1, 2, 1};
  const int Lnt[4]   = {11, 7, 3, 1};
  int Lsp[4]         = {4, 4, 8, 16};        // n-splits
  for (int i = 0; i < 4; i++)
    while (Lsp[i] > 1 && 2*Lnt[i]*Lsp[i] > cap) Lsp[i] >>= 1;

  const float* convin[4] = {xA /*unused for L0*/, xA, xB, xA};
  float*       wgout[4]  = {xA, xB, xA, xB};
  for (int i = 0; i < 4; i++) {
    float* ysumL = ysumb + (size_t)i*2*11*32;
    k_conv<<<dim3(256, Lnt[i], 2), 256, 0, stream>>>(
        convin[i], convin[i] + STRX, loadx, svcx, prWp, prbp, prWa, prba,
        Wtp, Wta, btp, bta, Zb, ybp, yba, ysumL, i, Ldd[i], Ltb[i], Lts[i]);
    k_mixm<<<dim3(16*Lsp[i], Lnt[i], 2), 256, 0, stream>>>(
        Ttp, Tta, epp, epa, ybp, yba, part, Ltb[i], Lts[i], Lnt[i], Lsp[i]);
    k_wg<<<dim3(256, Lnt[i], 2), 256, 0, stream>>>(
        part, ysumL, Wgp, Wga, bgp, bga, wgout[i], wgout[i] + STRX, i, Ltb[i], Lts[i], Lnt[i], Lsp[i]);
  }
  // final stream features at t=15 live in xB (layer 3 output)
  const float* fpp = xB + (size_t)15*N_E*32;
  const float* fpa = xB + STRX + (size_t)15*N_E*32;

  k_mlp<<<256,128,0,stream>>>(info, tra_feat, fpp, fpa, srv_emb, svc_emb,
                             qW0, qb0, qW1, qb1, qW2, qb2, qW3, qb3, qW4, qb4, qW5, qb5, out);
}